// Round 21
// baseline (287.616 us; speedup 1.0000x reference)
//
#include <hip/hip_runtime.h>
#include <hip/hip_bf16.h>

#define MODEL 2048
#define NHEAD 16
#define HDIM  128
#define BB    2
#define LL    2048
#define N1    (3*MODEL)      // 6144
#define MTOT  (BB*LL)        // 4096

typedef __hip_bfloat16 bf16;
typedef __attribute__((ext_vector_type(8))) short bf16x8;
typedef __attribute__((ext_vector_type(4))) float f32x4;

static __device__ __forceinline__ f32x4 mfma16(bf16x8 a, bf16x8 b, f32x4 c) {
  return __builtin_amdgcn_mfma_f32_16x16x32_bf16(a, b, c, 0, 0, 0);
}

// async global->LDS DMA, 16B per lane; LDS base wave-uniform, dest linear
static __device__ __forceinline__ void gl_lds16(const void* g, void* l) {
  __builtin_amdgcn_global_load_lds(
      (const __attribute__((address_space(1))) unsigned int*)g,
      (__attribute__((address_space(3))) unsigned int*)l, 16, 0, 0);
}

static __device__ __forceinline__ unsigned bfu(float x) {
  bf16 b = __float2bfloat16(x);
  return (unsigned)*reinterpret_cast<unsigned short*>(&b);
}

#define BARRIER __builtin_amdgcn_s_barrier()
#define SCHED0  __builtin_amdgcn_sched_barrier(0)
#define PRIO1 __builtin_amdgcn_s_setprio(1)
#define PRIO0 __builtin_amdgcn_s_setprio(0)

// ---------------- prep: f32 -> bf16 (vectorized x4) ----------------
__global__ void k_cvt(const float* __restrict__ in, bf16* __restrict__ out, int n4) {
  int i = blockIdx.x * blockDim.x + threadIdx.x;
  if (i < n4) {
    float4 v = ((const float4*)in)[i];
    bf16* o = out + (size_t)i * 4;
    o[0] = __float2bfloat16(v.x);
    o[1] = __float2bfloat16(v.y);
    o[2] = __float2bfloat16(v.z);
    o[3] = __float2bfloat16(v.w);
  }
}

// ---------------- prep: transpose f32 [R][C] -> bf16 [C][R] ----------------
__global__ __launch_bounds__(256)
void k_transpose(const float* __restrict__ in, bf16* __restrict__ out, int R, int C) {
  __shared__ float t[32][33];
  const int c0 = blockIdx.x * 32, r0 = blockIdx.y * 32;
  const int tx = threadIdx.x & 31;
  const int ty = threadIdx.x >> 5;   // 0..7
#pragma unroll
  for (int i = 0; i < 4; ++i)
    t[ty + 8*i][tx] = in[(size_t)(r0 + ty + 8*i) * C + c0 + tx];
  __syncthreads();
#pragma unroll
  for (int i = 0; i < 4; ++i)
    out[(size_t)(c0 + ty + 8*i) * R + r0 + tx] = __float2bfloat16(t[tx][ty + 8*i]);
}

// ====== 128x128 GEMM, BK=32, 3-buffer pipeline, 3 blocks/CU (r16-exact) ======
// r12-proven skeleton: 8 waves 2Mx4N, lockstep tile, distributed staging +
// collective barrier per tile [r8 lesson], mod-3 rotation with depth-2
// staging [r12 safety], slot swizzle [r6, 0-conflict], square XCD chunking
// [r12: per-XCD A panel L2-fits].
// EPI==1: RoPE + scatter Q/K row-major + V^T ; EPI==2: bias + f32 out.
template<int EPI>
__global__ __launch_bounds__(512, 4)
void k_gemmP(const bf16* __restrict__ A, const bf16* __restrict__ BT,
             int M, int N, int K,
             float* __restrict__ Cout, const float* __restrict__ bias,
             bf16* __restrict__ Qb, bf16* __restrict__ Kb, bf16* __restrict__ VTb,
             const float* __restrict__ cosT, const float* __restrict__ sinT)
{
  constexpr int ABUF = 8192;           // one A tile (128 rows x 64B)
  constexpr int BBUF = 8192;
  constexpr int AREG = 3 * ABUF;       // 24576
  extern __shared__ char smem[];       // 49152 B

  const int tid = threadIdx.x;
  const int wid = tid >> 6, lane = tid & 63;
  const int wm = wid >> 2, wn = wid & 3;       // wave grid 2(M) x 4(N)
  const int lr = lane & 15, lkg = lane >> 4;

  // XCD chunk map (bid%8 = XCD): XCD=(mquarter, nhalf) owns an
  // 8 m-tile x (nbx/2) n-tile chunk, m-inner traversal (A panel L2-fits).
  const int nbx = N >> 7;
  const int xcd = blockIdx.x & 7;
  const int i   = blockIdx.x >> 3;
  const int m0 = (((xcd >> 1) << 3) + (i & 7)) << 7;
  const int n0 = ((xcd & 1) * (nbx >> 1) + (i >> 3)) << 7;

  // staging: wave wid owns 16 rows; source slot carries inverse swizzle
  const int scol = ((lane & 3) ^ ((lane >> 3) & 3)) * 8;   // bf16 elems
  const bf16* Asrc = A  + (size_t)(m0 + wid*16 + (lane >> 2)) * K + scol;
  const bf16* Bsrc = BT + (size_t)(n0 + wid*16 + (lane >> 2)) * K + scol;

  auto stageA = [&](int t) {
    gl_lds16(Asrc + t*32, smem + (t % 3)*ABUF + wid*1024);
  };
  auto stageB = [&](int t) {
    gl_lds16(Bsrc + t*32, smem + AREG + (t % 3)*BBUF + wid*1024);
  };

  // ds_read fragment bases (row = 64B, slot XOR-swizzled by row bits 1-2)
  const int slotX = (lkg ^ ((lr >> 1) & 3)) * 16;
  const int aBase = wm*4096 + lr*64 + slotX;   // rows wm*64 + mf*16 + lr
  const int bBase = wn*2048 + lr*64 + slotX;   // rows wn*32 + nf*16 + lr

  const f32x4 vzero = {0.f, 0.f, 0.f, 0.f};
  f32x4 acc[4][2];
#pragma unroll
  for (int ii = 0; ii < 4; ++ii)
#pragma unroll
    for (int j = 0; j < 2; ++j) acc[ii][j] = vzero;

  const int nt = K >> 5;              // K-tiles of 32 (>= 3)

  // prologue: stage tiles 0,1 -> wait until tile 0's 2 loads complete
  stageA(0); stageB(0); stageA(1); stageB(1);
  asm volatile("s_waitcnt vmcnt(2)" ::: "memory");
  SCHED0; BARRIER;

  for (int t = 0; t < nt; ++t) {
    const int bufA = (t % 3) * ABUF;
    const int bufB = AREG + (t % 3) * BBUF;
    const int ts   = (t + 2 < nt) ? t + 2 : nt - 1;   // clamp: same-data dup
    bf16x8 aFr[4], bFr[2];

#pragma unroll
    for (int mf = 0; mf < 4; ++mf)
      aFr[mf] = *(const bf16x8*)(smem + bufA + aBase + mf*1024);
#pragma unroll
    for (int nf = 0; nf < 2; ++nf)
      bFr[nf] = *(const bf16x8*)(smem + bufB + bBase + nf*1024);
    stageA(ts); stageB(ts);

    // no explicit lgkm drain: compiler emits fine-grained lgkmcnt per dep
    PRIO1;
#pragma unroll
    for (int mf = 0; mf < 4; ++mf)
#pragma unroll
      for (int nf = 0; nf < 2; ++nf)
        acc[mf][nf] = mfma16(aFr[mf], bFr[nf], acc[mf][nf]);
    PRIO0;
    // complete tile t+1's loads (only stage(t+2)'s 2 loads stay in flight)
    asm volatile("s_waitcnt vmcnt(2)" ::: "memory");
    SCHED0;
    BARRIER;                          // collective: tile t+1 visible to all
  }

  if constexpr (EPI == 1) {
    const float inv_sqrt_d = 0.08838834764831845f;  // 1/sqrt(128)
#pragma unroll
    for (int nf = 0; nf < 2; ++nf) {
      const int gcb = n0 + wn*32 + nf*16;           // wave-uniform, mult of 16
      const int section = gcb >> 11;                // 0=q 1=k 2=v
      const int cc = (gcb & 2047) + lr;
      const int h = cc >> 7, d = cc & 127;
#pragma unroll
      for (int mf = 0; mf < 4; ++mf) {
#pragma unroll
        for (int reg = 0; reg < 4; ++reg) {
          const int grow = m0 + wm*64 + mf*16 + lkg*4 + reg;
          const int bidx = grow >> 11, lseq = grow & 2047;
          float val = acc[mf][nf][reg];
          if (section < 2) {
            float p = __shfl_xor(val, 1);           // RoPE pair partner
            const int fi = d >> 1;
            float cv = cosT[(size_t)lseq * 64 + fi];
            float sv = sinT[(size_t)lseq * 64 + fi];
            float r = (d & 1) ? fmaf(p, sv, val * cv)
                              : fmaf(val, cv, -p * sv);
            if (section == 0) {
              r *= inv_sqrt_d;
              Qb[((size_t)(bidx*NHEAD + h) * LL + lseq) * HDIM + d] = __float2bfloat16(r);
            } else {
              Kb[((size_t)(bidx*NHEAD + h) * LL + lseq) * HDIM + d] = __float2bfloat16(r);
            }
          } else {
            VTb[((size_t)(bidx*NHEAD + h) * HDIM + d) * LL + lseq] = __float2bfloat16(val);
          }
        }
      }
    }
  } else {
#pragma unroll
    for (int nf = 0; nf < 2; ++nf) {
      const int gcol = n0 + wn*32 + nf*16 + lr;
      const float bv = bias[gcol];
#pragma unroll
      for (int mf = 0; mf < 4; ++mf) {
#pragma unroll
        for (int reg = 0; reg < 4; ++reg) {
          const int grow = m0 + wm*64 + mf*16 + lkg*4 + reg;
          Cout[(size_t)grow * N + gcol] = acc[mf][nf][reg] + bv;
        }
      }
    }
  }
}

// ---------------- flash attention (r21): merged pair + K/V LDS double-buffer
// Waves 0-3 own q-tile (15-bx), waves 4-7 own bx; staged K/V serves both.
// r21: K/V double-buffered by kt&1 -> ONE __syncthreads per kv-tile.
// Per-wave order: ds_write(tile kt -> buf kt&1); global-load kt+1 -> regs;
// barrier; compute(buf kt&1).  Safety: writer of buf b at iter kt crossed
// barrier(kt-1), readers of b (compute at kt-2) precede it -> no WAR; the
// barrier publishes this iter's writes -> no RAW. LDS 108.5KB, 1 block/CU
// (unchanged: grid is 256 blocks). Per-wave body = r14-verified swapped-QK^T.
__global__ __launch_bounds__(512)
void k_attn(const bf16* __restrict__ Qb, const bf16* __restrict__ Kb,
            const bf16* __restrict__ VTb, bf16* __restrict__ attnA)
{
  extern __shared__ char asmem[];
  // K buf b: asmem + b*17408            ([64][136] bf16)
  // V buf b: asmem + 34816 + b*18432    ([128][72] bf16)
  // Ps:      asmem + 71680              ([8][32][72] bf16)
  bf16* PsB = (bf16*)(asmem + 71680);

  const int bh  = blockIdx.y;
  const int bx  = blockIdx.x;                 // 0..7
  const int tid = threadIdx.x;                // 0..511
  const int wid = tid >> 6, lane = tid & 63;
  const int lr  = lane & 15, lkg = lane >> 4;

  const bf16* Qh = Qb  + (size_t)bh * LL * HDIM;
  const bf16* Kh = Kb  + (size_t)bh * LL * HDIM;
  const bf16* Vh = VTb + (size_t)bh * HDIM * LL;
  const int b = bh >> 4, h = bh & 15;
  const f32x4 vzero = {0.f, 0.f, 0.f, 0.f};

  const int qt  = (wid < 4) ? (15 - bx) : bx;   // heavy tile on waves 0-3
  const int q0w = qt * 128 + (wid & 3) * 32;

  bf16x8 qf[2][4];
#pragma unroll
  for (int qr = 0; qr < 2; ++qr)
#pragma unroll
    for (int kk = 0; kk < 4; ++kk)
      qf[qr][kk] = *(const bf16x8*)(Qh + (size_t)(q0w + qr*16 + lr) * HDIM + kk*32 + lkg*8);

  f32x4 oacc[2][8];
#pragma unroll
  for (int qr = 0; qr < 2; ++qr)
#pragma unroll
    for (int db = 0; db < 8; ++db) oacc[qr][db] = vzero;
  float ml[2] = {-INFINITY, -INFINITY};
  float ll[2] = {0.f, 0.f};

  const int NT = (15 - bx) * 2 + 2;   // heavy tile's kv-tile count (max)

  // prologue: tile 0 into regs
  bf16x8 kpre[2], vpre[2];
#pragma unroll
  for (int j = 0; j < 2; ++j) {
    const int c = j*512 + tid;
    kpre[j] = *(const bf16x8*)(Kh + (size_t)(c >> 4) * HDIM + (c & 15) * 8);
    vpre[j] = *(const bf16x8*)(Vh + (size_t)(c >> 3) * LL + (c & 7) * 8);
  }

  for (int kt = 0; kt < NT; ++kt) {
    const int kbase = kt * 64;
    bf16* KsB = (bf16*)(asmem + (kt & 1) * 17408);
    bf16* VsB = (bf16*)(asmem + 34816 + (kt & 1) * 18432);

    // write tile kt into buf kt&1 (WAR-safe: buf's readers were iter kt-2,
    // all waves crossed barrier(kt-1) before this point)
#pragma unroll
    for (int j = 0; j < 2; ++j) {
      const int c = j*512 + tid;
      *(bf16x8*)&KsB[(c >> 4) * 136 + (c & 15) * 8] = kpre[j];
      *(bf16x8*)&VsB[(c >> 3) * 72  + (c & 7)  * 8] = vpre[j];
    }
    // issue next-tile global loads (consumed after next barrier)
    if (kt + 1 < NT) {
#pragma unroll
      for (int j = 0; j < 2; ++j) {
        const int c = j*512 + tid;
        kpre[j] = *(const bf16x8*)(Kh + (size_t)((kt+1)*64 + (c >> 4)) * HDIM + (c & 15) * 8);
        vpre[j] = *(const bf16x8*)(Vh + (size_t)(c >> 3) * LL + (kt+1)*64 + (c & 7) * 8);
      }
    }
    __syncthreads();                  // single barrier: publish + guard

    if (kbase <= q0w + 31) {
      f32x4 s2[2][4];
#pragma unroll
      for (int qr = 0; qr < 2; ++qr)
#pragma unroll
        for (int c = 0; c < 4; ++c) s2[qr][c] = vzero;
#pragma unroll
      for (int c = 0; c < 4; ++c) {
        bf16x8 kf[4];
#pragma unroll
        for (int kk = 0; kk < 4; ++kk)
          kf[kk] = *(const bf16x8*)&KsB[(c*16 + lr) * 136 + kk*32 + lkg*8];
#pragma unroll
        for (int qr = 0; qr < 2; ++qr)
#pragma unroll
          for (int kk = 0; kk < 4; ++kk)
            s2[qr][c] = mfma16(kf[kk], qf[qr][kk], s2[qr][c]);
      }
#pragma unroll
      for (int qr = 0; qr < 2; ++qr) {
        const int qrow = q0w + qr*16 + lr;
        float pv[4][4];
#pragma unroll
        for (int c = 0; c < 4; ++c)
#pragma unroll
          for (int reg = 0; reg < 4; ++reg) {
            const int kv = kbase + c*16 + lkg*4 + reg;
            pv[c][reg] = (kv <= qrow) ? s2[qr][c][reg] : -INFINITY;
          }
        float tm = pv[0][0];
#pragma unroll
        for (int c = 0; c < 4; ++c)
#pragma unroll
          for (int reg = 0; reg < 4; ++reg)
            if (c || reg) tm = fmaxf(tm, pv[c][reg]);
        tm = fmaxf(tm, __shfl_xor(tm, 16));
        tm = fmaxf(tm, __shfl_xor(tm, 32));
        const float mnew = fmaxf(ml[qr], tm);
        const float scl  = __expf(ml[qr] - mnew);
        ml[qr] = mnew;
        float rs = 0.f;
#pragma unroll
        for (int c = 0; c < 4; ++c)
#pragma unroll
          for (int reg = 0; reg < 4; ++reg) {
            pv[c][reg] = __expf(pv[c][reg] - mnew);
            rs += pv[c][reg];
          }
        rs += __shfl_xor(rs, 16);
        rs += __shfl_xor(rs, 32);
        ll[qr] = ll[qr] * scl + rs;
#pragma unroll
        for (int c = 0; c < 4; ++c) {
          unsigned lo = bfu(pv[c][0]) | (bfu(pv[c][1]) << 16);
          unsigned hi = bfu(pv[c][2]) | (bfu(pv[c][3]) << 16);
          *(uint2*)&PsB[(wid*32 + qr*16 + lr) * 72 + c*16 + lkg*4] = make_uint2(lo, hi);
        }
        float sr[4];
#pragma unroll
        for (int reg = 0; reg < 4; ++reg) sr[reg] = __shfl(scl, lkg*4 + reg);
#pragma unroll
        for (int db = 0; db < 8; ++db) {
          oacc[qr][db][0] *= sr[0]; oacc[qr][db][1] *= sr[1];
          oacc[qr][db][2] *= sr[2]; oacc[qr][db][3] *= sr[3];
        }
      }
      asm volatile("s_waitcnt lgkmcnt(0)" ::: "memory");
      __builtin_amdgcn_sched_barrier(0);
      bf16x8 pf[2][2];
#pragma unroll
      for (int qr = 0; qr < 2; ++qr)
#pragma unroll
        for (int k2 = 0; k2 < 2; ++k2)
          pf[qr][k2] = *(const bf16x8*)&PsB[(wid*32 + qr*16 + lr) * 72 + k2*32 + lkg*8];
#pragma unroll
      for (int db = 0; db < 8; ++db) {
        bf16x8 vf0 = *(const bf16x8*)&VsB[(db*16 + lr) * 72 + lkg*8];
        bf16x8 vf1 = *(const bf16x8*)&VsB[(db*16 + lr) * 72 + 32 + lkg*8];
#pragma unroll
        for (int qr = 0; qr < 2; ++qr) {
          oacc[qr][db] = mfma16(pf[qr][0], vf0, oacc[qr][db]);
          oacc[qr][db] = mfma16(pf[qr][1], vf1, oacc[qr][db]);
        }
      }
    }
  }

#pragma unroll
  for (int qr = 0; qr < 2; ++qr) {
    const float myinv = 1.0f / ll[qr];
    float li[4];
#pragma unroll
    for (int reg = 0; reg < 4; ++reg) li[reg] = __shfl(myinv, lkg*4 + reg);
#pragma unroll
    for (int reg = 0; reg < 4; ++reg) {
      const int row = q0w + qr*16 + lkg*4 + reg;
      bf16* dst = attnA + ((size_t)(b*LL + row)) * MODEL + h * HDIM;
#pragma unroll
      for (int db = 0; db < 8; ++db)
        dst[db*16 + lr] = __float2bfloat16(oacc[qr][db][reg] * li[reg]);
    }
  }
}

// ---------------- launch ----------------
extern "C" void kernel_launch(void* const* d_in, const int* in_sizes, int n_in,
                              void* d_out, int out_size, void* d_ws, size_t ws_size,
                              hipStream_t stream)
{
  const float* x    = (const float*)d_in[0];
  const float* cosT = (const float*)d_in[1];
  const float* sinT = (const float*)d_in[2];
  const float* Wqkv = (const float*)d_in[3];
  const float* Wc   = (const float*)d_in[4];
  const float* bc   = (const float*)d_in[5];
  float* out = (float*)d_out;

  // workspace layout (bytes):
  //   x16    @ 0         : 16,777,216   (reused as attnA later)
  //   WqkvT  @ 16777216  : 25,165,824
  //   WcT    @ 41943040  :  8,388,608
  //   Qb     @ 50331648  : 16,777,216
  //   Kb     @ 67108864  : 16,777,216
  //   VTb    @ 83886080  : 16,777,216   -> total 100,663,296 B
  if (ws_size < 100663296u) return;
  char* w = (char*)d_ws;
  bf16* x16   = (bf16*)(w);
  bf16* WqkvT = (bf16*)(w + (size_t)16777216);
  bf16* WcT   = (bf16*)(w + (size_t)41943040);
  bf16* Qb    = (bf16*)(w + (size_t)50331648);
  bf16* Kb    = (bf16*)(w + (size_t)67108864);
  bf16* VTb   = (bf16*)(w + (size_t)83886080);
  bf16* attnA = x16;   // overlay: x16 dead after GEMM1

  // allow dynamic LDS (idempotent; not a stream op -> capture-safe)
  hipFuncSetAttribute(reinterpret_cast<const void*>(&k_gemmP<1>),
                      hipFuncAttributeMaxDynamicSharedMemorySize, 49152);
  hipFuncSetAttribute(reinterpret_cast<const void*>(&k_gemmP<2>),
                      hipFuncAttributeMaxDynamicSharedMemorySize, 49152);
  hipFuncSetAttribute(reinterpret_cast<const void*>(&k_attn),
                      hipFuncAttributeMaxDynamicSharedMemorySize, 108544);

  k_cvt<<<(MTOT*MODEL/4 + 255)/256, 256, 0, stream>>>(x, x16, MTOT*MODEL/4);
  k_transpose<<<dim3(N1/32,    MODEL/32), 256, 0, stream>>>(Wqkv, WqkvT, MODEL, N1);
  k_transpose<<<dim3(MODEL/32, MODEL/32), 256, 0, stream>>>(Wc,   WcT,   MODEL, MODEL);

  // grid 48*32 = 1536 blocks (3 blocks/CU -> 2 exact rounds of 768)
  k_gemmP<1><<<(N1/128)*(MTOT/128), 512, 49152, stream>>>(
      x16, WqkvT, MTOT, N1, MODEL,
      nullptr, nullptr, Qb, Kb, VTb, cosT, sinT);

  // grid 8*32 = 256 blocks, 8 waves each, paired q-tiles share staged KV
  k_attn<<<dim3(8, BB*NHEAD), 512, 108544, stream>>>(Qb, Kb, VTb, attnA);

  // grid 16*32 = 512 blocks
  k_gemmP<2><<<(MODEL/128)*(MTOT/128), 512, 49152, stream>>>(
      attnA, WcT, MTOT, MODEL, MODEL,
      out, bc, nullptr, nullptr, nullptr, nullptr, nullptr);
}

// Round 22
// 287.357 us; speedup vs baseline: 1.0009x; 1.0009x over previous
//
#include <hip/hip_runtime.h>
#include <hip/hip_bf16.h>

#define MODEL 2048
#define NHEAD 16
#define HDIM  128
#define BB    2
#define LL    2048
#define N1    (3*MODEL)      // 6144
#define MTOT  (BB*LL)        // 4096

typedef __hip_bfloat16 bf16;
typedef __attribute__((ext_vector_type(8))) short bf16x8;
typedef __attribute__((ext_vector_type(4))) float f32x4;

static __device__ __forceinline__ f32x4 mfma16(bf16x8 a, bf16x8 b, f32x4 c) {
  return __builtin_amdgcn_mfma_f32_16x16x32_bf16(a, b, c, 0, 0, 0);
}

// async global->LDS DMA, 16B per lane; LDS base wave-uniform, dest linear
static __device__ __forceinline__ void gl_lds16(const void* g, void* l) {
  __builtin_amdgcn_global_load_lds(
      (const __attribute__((address_space(1))) unsigned int*)g,
      (__attribute__((address_space(3))) unsigned int*)l, 16, 0, 0);
}

static __device__ __forceinline__ unsigned bfu(float x) {
  bf16 b = __float2bfloat16(x);
  return (unsigned)*reinterpret_cast<unsigned short*>(&b);
}

#define BARRIER __builtin_amdgcn_s_barrier()
#define SCHED0  __builtin_amdgcn_sched_barrier(0)
#define PRIO1 __builtin_amdgcn_s_setprio(1)
#define PRIO0 __builtin_amdgcn_s_setprio(0)

// ---------------- prep: f32 -> bf16 (vectorized x4) ----------------
__global__ void k_cvt(const float* __restrict__ in, bf16* __restrict__ out, int n4) {
  int i = blockIdx.x * blockDim.x + threadIdx.x;
  if (i < n4) {
    float4 v = ((const float4*)in)[i];
    bf16* o = out + (size_t)i * 4;
    o[0] = __float2bfloat16(v.x);
    o[1] = __float2bfloat16(v.y);
    o[2] = __float2bfloat16(v.z);
    o[3] = __float2bfloat16(v.w);
  }
}

// ---------------- prep: transpose f32 [R][C] -> bf16 [C][R] ----------------
__global__ __launch_bounds__(256)
void k_transpose(const float* __restrict__ in, bf16* __restrict__ out, int R, int C) {
  __shared__ float t[32][33];
  const int c0 = blockIdx.x * 32, r0 = blockIdx.y * 32;
  const int tx = threadIdx.x & 31;
  const int ty = threadIdx.x >> 5;   // 0..7
#pragma unroll
  for (int i = 0; i < 4; ++i)
    t[ty + 8*i][tx] = in[(size_t)(r0 + ty + 8*i) * C + c0 + tx];
  __syncthreads();
#pragma unroll
  for (int i = 0; i < 4; ++i)
    out[(size_t)(c0 + ty + 8*i) * R + r0 + tx] = __float2bfloat16(t[tx][ty + 8*i]);
}

// ====== 128x128 GEMM, BK=32, 3-buffer pipeline, 3 blocks/CU (r16-exact) ======
// r12-proven skeleton: 8 waves 2Mx4N, lockstep tile, distributed staging +
// collective barrier per tile [r8 lesson], mod-3 rotation with depth-2
// staging [r12 safety], slot swizzle [r6, 0-conflict], square XCD chunking
// [r12: per-XCD A panel L2-fits].
// EPI==1: RoPE + scatter Q/K row-major + V^T ; EPI==2: bias + f32 out.
template<int EPI>
__global__ __launch_bounds__(512, 4)
void k_gemmP(const bf16* __restrict__ A, const bf16* __restrict__ BT,
             int M, int N, int K,
             float* __restrict__ Cout, const float* __restrict__ bias,
             bf16* __restrict__ Qb, bf16* __restrict__ Kb, bf16* __restrict__ VTb,
             const float* __restrict__ cosT, const float* __restrict__ sinT)
{
  constexpr int ABUF = 8192;           // one A tile (128 rows x 64B)
  constexpr int BBUF = 8192;
  constexpr int AREG = 3 * ABUF;       // 24576
  extern __shared__ char smem[];       // 49152 B

  const int tid = threadIdx.x;
  const int wid = tid >> 6, lane = tid & 63;
  const int wm = wid >> 2, wn = wid & 3;       // wave grid 2(M) x 4(N)
  const int lr = lane & 15, lkg = lane >> 4;

  // XCD chunk map (bid%8 = XCD): XCD=(mquarter, nhalf) owns an
  // 8 m-tile x (nbx/2) n-tile chunk, m-inner traversal (A panel L2-fits).
  const int nbx = N >> 7;
  const int xcd = blockIdx.x & 7;
  const int i   = blockIdx.x >> 3;
  const int m0 = (((xcd >> 1) << 3) + (i & 7)) << 7;
  const int n0 = ((xcd & 1) * (nbx >> 1) + (i >> 3)) << 7;

  // staging: wave wid owns 16 rows; source slot carries inverse swizzle
  const int scol = ((lane & 3) ^ ((lane >> 3) & 3)) * 8;   // bf16 elems
  const bf16* Asrc = A  + (size_t)(m0 + wid*16 + (lane >> 2)) * K + scol;
  const bf16* Bsrc = BT + (size_t)(n0 + wid*16 + (lane >> 2)) * K + scol;

  auto stageA = [&](int t) {
    gl_lds16(Asrc + t*32, smem + (t % 3)*ABUF + wid*1024);
  };
  auto stageB = [&](int t) {
    gl_lds16(Bsrc + t*32, smem + AREG + (t % 3)*BBUF + wid*1024);
  };

  // ds_read fragment bases (row = 64B, slot XOR-swizzled by row bits 1-2)
  const int slotX = (lkg ^ ((lr >> 1) & 3)) * 16;
  const int aBase = wm*4096 + lr*64 + slotX;   // rows wm*64 + mf*16 + lr
  const int bBase = wn*2048 + lr*64 + slotX;   // rows wn*32 + nf*16 + lr

  const f32x4 vzero = {0.f, 0.f, 0.f, 0.f};
  f32x4 acc[4][2];
#pragma unroll
  for (int ii = 0; ii < 4; ++ii)
#pragma unroll
    for (int j = 0; j < 2; ++j) acc[ii][j] = vzero;

  const int nt = K >> 5;              // K-tiles of 32 (>= 3)

  // prologue: stage tiles 0,1 -> wait until tile 0's 2 loads complete
  stageA(0); stageB(0); stageA(1); stageB(1);
  asm volatile("s_waitcnt vmcnt(2)" ::: "memory");
  SCHED0; BARRIER;

  for (int t = 0; t < nt; ++t) {
    const int bufA = (t % 3) * ABUF;
    const int bufB = AREG + (t % 3) * BBUF;
    const int ts   = (t + 2 < nt) ? t + 2 : nt - 1;   // clamp: same-data dup
    bf16x8 aFr[4], bFr[2];

#pragma unroll
    for (int mf = 0; mf < 4; ++mf)
      aFr[mf] = *(const bf16x8*)(smem + bufA + aBase + mf*1024);
#pragma unroll
    for (int nf = 0; nf < 2; ++nf)
      bFr[nf] = *(const bf16x8*)(smem + bufB + bBase + nf*1024);
    stageA(ts); stageB(ts);

    // no explicit lgkm drain: compiler emits fine-grained lgkmcnt per dep
    PRIO1;
#pragma unroll
    for (int mf = 0; mf < 4; ++mf)
#pragma unroll
      for (int nf = 0; nf < 2; ++nf)
        acc[mf][nf] = mfma16(aFr[mf], bFr[nf], acc[mf][nf]);
    PRIO0;
    // complete tile t+1's loads (only stage(t+2)'s 2 loads stay in flight)
    asm volatile("s_waitcnt vmcnt(2)" ::: "memory");
    SCHED0;
    BARRIER;                          // collective: tile t+1 visible to all
  }

  if constexpr (EPI == 1) {
    const float inv_sqrt_d = 0.08838834764831845f;  // 1/sqrt(128)
#pragma unroll
    for (int nf = 0; nf < 2; ++nf) {
      const int gcb = n0 + wn*32 + nf*16;           // wave-uniform, mult of 16
      const int section = gcb >> 11;                // 0=q 1=k 2=v
      const int cc = (gcb & 2047) + lr;
      const int h = cc >> 7, d = cc & 127;
#pragma unroll
      for (int mf = 0; mf < 4; ++mf) {
#pragma unroll
        for (int reg = 0; reg < 4; ++reg) {
          const int grow = m0 + wm*64 + mf*16 + lkg*4 + reg;
          const int bidx = grow >> 11, lseq = grow & 2047;
          float val = acc[mf][nf][reg];
          if (section < 2) {
            float p = __shfl_xor(val, 1);           // RoPE pair partner
            const int fi = d >> 1;
            float cv = cosT[(size_t)lseq * 64 + fi];
            float sv = sinT[(size_t)lseq * 64 + fi];
            float r = (d & 1) ? fmaf(p, sv, val * cv)
                              : fmaf(val, cv, -p * sv);
            if (section == 0) {
              r *= inv_sqrt_d;
              Qb[((size_t)(bidx*NHEAD + h) * LL + lseq) * HDIM + d] = __float2bfloat16(r);
            } else {
              Kb[((size_t)(bidx*NHEAD + h) * LL + lseq) * HDIM + d] = __float2bfloat16(r);
            }
          } else {
            VTb[((size_t)(bidx*NHEAD + h) * HDIM + d) * LL + lseq] = __float2bfloat16(val);
          }
        }
      }
    }
  } else {
#pragma unroll
    for (int nf = 0; nf < 2; ++nf) {
      const int gcol = n0 + wn*32 + nf*16 + lr;
      const float bv = bias[gcol];
#pragma unroll
      for (int mf = 0; mf < 4; ++mf) {
#pragma unroll
        for (int reg = 0; reg < 4; ++reg) {
          const int grow = m0 + wm*64 + mf*16 + lkg*4 + reg;
          Cout[(size_t)grow * N + gcol] = acc[mf][nf][reg] + bv;
        }
      }
    }
  }
}

// ---------------- flash attention (r22): merged pair + dbuf + T13 defer-max
// Waves 0-3 own q-tile (15-bx), waves 4-7 own bx; staged K/V serves both.
// K/V double-buffered by kt&1 -> one __syncthreads per kv-tile (r21).
// r22: T13 defer-max -- when __all(tm <= ml+8) (wave-uniform), keep the old
// running max: skip exp(ml-mnew), the 64-mult oacc rescale and 4 shfl
// broadcasts. P bounded by e^8 (bf16-safe, same relative precision); ll
// accumulation f32-safe. First tile (ml=-inf) and fully-masked lanes
// (tm=-inf) both resolve to the correct path (derived r22).
__global__ __launch_bounds__(512)
void k_attn(const bf16* __restrict__ Qb, const bf16* __restrict__ Kb,
            const bf16* __restrict__ VTb, bf16* __restrict__ attnA)
{
  extern __shared__ char asmem[];
  // K buf b: asmem + b*17408            ([64][136] bf16)
  // V buf b: asmem + 34816 + b*18432    ([128][72] bf16)
  // Ps:      asmem + 71680              ([8][32][72] bf16)
  bf16* PsB = (bf16*)(asmem + 71680);

  const int bh  = blockIdx.y;
  const int bx  = blockIdx.x;                 // 0..7
  const int tid = threadIdx.x;                // 0..511
  const int wid = tid >> 6, lane = tid & 63;
  const int lr  = lane & 15, lkg = lane >> 4;

  const bf16* Qh = Qb  + (size_t)bh * LL * HDIM;
  const bf16* Kh = Kb  + (size_t)bh * LL * HDIM;
  const bf16* Vh = VTb + (size_t)bh * HDIM * LL;
  const int b = bh >> 4, h = bh & 15;
  const f32x4 vzero = {0.f, 0.f, 0.f, 0.f};

  const int qt  = (wid < 4) ? (15 - bx) : bx;   // heavy tile on waves 0-3
  const int q0w = qt * 128 + (wid & 3) * 32;

  bf16x8 qf[2][4];
#pragma unroll
  for (int qr = 0; qr < 2; ++qr)
#pragma unroll
    for (int kk = 0; kk < 4; ++kk)
      qf[qr][kk] = *(const bf16x8*)(Qh + (size_t)(q0w + qr*16 + lr) * HDIM + kk*32 + lkg*8);

  f32x4 oacc[2][8];
#pragma unroll
  for (int qr = 0; qr < 2; ++qr)
#pragma unroll
    for (int db = 0; db < 8; ++db) oacc[qr][db] = vzero;
  float ml[2] = {-INFINITY, -INFINITY};
  float ll[2] = {0.f, 0.f};

  const int NT = (15 - bx) * 2 + 2;   // heavy tile's kv-tile count (max)

  // prologue: tile 0 into regs
  bf16x8 kpre[2], vpre[2];
#pragma unroll
  for (int j = 0; j < 2; ++j) {
    const int c = j*512 + tid;
    kpre[j] = *(const bf16x8*)(Kh + (size_t)(c >> 4) * HDIM + (c & 15) * 8);
    vpre[j] = *(const bf16x8*)(Vh + (size_t)(c >> 3) * LL + (c & 7) * 8);
  }

  for (int kt = 0; kt < NT; ++kt) {
    const int kbase = kt * 64;
    bf16* KsB = (bf16*)(asmem + (kt & 1) * 17408);
    bf16* VsB = (bf16*)(asmem + 34816 + (kt & 1) * 18432);

    // write tile kt into buf kt&1 (WAR-safe: buf's readers were iter kt-2,
    // all waves crossed barrier(kt-1) before this point)
#pragma unroll
    for (int j = 0; j < 2; ++j) {
      const int c = j*512 + tid;
      *(bf16x8*)&KsB[(c >> 4) * 136 + (c & 15) * 8] = kpre[j];
      *(bf16x8*)&VsB[(c >> 3) * 72  + (c & 7)  * 8] = vpre[j];
    }
    // issue next-tile global loads (consumed after next barrier)
    if (kt + 1 < NT) {
#pragma unroll
      for (int j = 0; j < 2; ++j) {
        const int c = j*512 + tid;
        kpre[j] = *(const bf16x8*)(Kh + (size_t)((kt+1)*64 + (c >> 4)) * HDIM + (c & 15) * 8);
        vpre[j] = *(const bf16x8*)(Vh + (size_t)(c >> 3) * LL + (kt+1)*64 + (c & 7) * 8);
      }
    }
    __syncthreads();                  // single barrier: publish + guard

    if (kbase <= q0w + 31) {
      f32x4 s2[2][4];
#pragma unroll
      for (int qr = 0; qr < 2; ++qr)
#pragma unroll
        for (int c = 0; c < 4; ++c) s2[qr][c] = vzero;
#pragma unroll
      for (int c = 0; c < 4; ++c) {
        bf16x8 kf[4];
#pragma unroll
        for (int kk = 0; kk < 4; ++kk)
          kf[kk] = *(const bf16x8*)&KsB[(c*16 + lr) * 136 + kk*32 + lkg*8];
#pragma unroll
        for (int qr = 0; qr < 2; ++qr)
#pragma unroll
          for (int kk = 0; kk < 4; ++kk)
            s2[qr][c] = mfma16(kf[kk], qf[qr][kk], s2[qr][c]);
      }
#pragma unroll
      for (int qr = 0; qr < 2; ++qr) {
        const int qrow = q0w + qr*16 + lr;
        float pv[4][4];
#pragma unroll
        for (int c = 0; c < 4; ++c)
#pragma unroll
          for (int reg = 0; reg < 4; ++reg) {
            const int kv = kbase + c*16 + lkg*4 + reg;
            pv[c][reg] = (kv <= qrow) ? s2[qr][c][reg] : -INFINITY;
          }
        float tm = pv[0][0];
#pragma unroll
        for (int c = 0; c < 4; ++c)
#pragma unroll
          for (int reg = 0; reg < 4; ++reg)
            if (c || reg) tm = fmaxf(tm, pv[c][reg]);
        tm = fmaxf(tm, __shfl_xor(tm, 16));
        tm = fmaxf(tm, __shfl_xor(tm, 32));
        // T13 defer-max: if the new tile max doesn't exceed ml+8 on ANY
        // lane, keep ml (P bounded by e^8) and skip the rescale entirely.
        if (__all(tm <= ml[qr] + 8.0f)) {
          float rs = 0.f;
#pragma unroll
          for (int c = 0; c < 4; ++c)
#pragma unroll
            for (int reg = 0; reg < 4; ++reg) {
              pv[c][reg] = __expf(pv[c][reg] - ml[qr]);
              rs += pv[c][reg];
            }
          rs += __shfl_xor(rs, 16);
          rs += __shfl_xor(rs, 32);
          ll[qr] += rs;
        } else {
          const float mnew = fmaxf(ml[qr], tm);
          const float scl  = __expf(ml[qr] - mnew);
          ml[qr] = mnew;
          float rs = 0.f;
#pragma unroll
          for (int c = 0; c < 4; ++c)
#pragma unroll
            for (int reg = 0; reg < 4; ++reg) {
              pv[c][reg] = __expf(pv[c][reg] - mnew);
              rs += pv[c][reg];
            }
          rs += __shfl_xor(rs, 16);
          rs += __shfl_xor(rs, 32);
          ll[qr] = ll[qr] * scl + rs;
          float sr[4];
#pragma unroll
          for (int reg = 0; reg < 4; ++reg) sr[reg] = __shfl(scl, lkg*4 + reg);
#pragma unroll
          for (int db = 0; db < 8; ++db) {
            oacc[qr][db][0] *= sr[0]; oacc[qr][db][1] *= sr[1];
            oacc[qr][db][2] *= sr[2]; oacc[qr][db][3] *= sr[3];
          }
        }
#pragma unroll
        for (int c = 0; c < 4; ++c) {
          unsigned lo = bfu(pv[c][0]) | (bfu(pv[c][1]) << 16);
          unsigned hi = bfu(pv[c][2]) | (bfu(pv[c][3]) << 16);
          *(uint2*)&PsB[(wid*32 + qr*16 + lr) * 72 + c*16 + lkg*4] = make_uint2(lo, hi);
        }
      }
      asm volatile("s_waitcnt lgkmcnt(0)" ::: "memory");
      __builtin_amdgcn_sched_barrier(0);
      bf16x8 pf[2][2];
#pragma unroll
      for (int qr = 0; qr < 2; ++qr)
#pragma unroll
        for (int k2 = 0; k2 < 2; ++k2)
          pf[qr][k2] = *(const bf16x8*)&PsB[(wid*32 + qr*16 + lr) * 72 + k2*32 + lkg*8];
#pragma unroll
      for (int db = 0; db < 8; ++db) {
        bf16x8 vf0 = *(const bf16x8*)&VsB[(db*16 + lr) * 72 + lkg*8];
        bf16x8 vf1 = *(const bf16x8*)&VsB[(db*16 + lr) * 72 + 32 + lkg*8];
#pragma unroll
        for (int qr = 0; qr < 2; ++qr) {
          oacc[qr][db] = mfma16(pf[qr][0], vf0, oacc[qr][db]);
          oacc[qr][db] = mfma16(pf[qr][1], vf1, oacc[qr][db]);
        }
      }
    }
  }

#pragma unroll
  for (int qr = 0; qr < 2; ++qr) {
    const float myinv = 1.0f / ll[qr];
    float li[4];
#pragma unroll
    for (int reg = 0; reg < 4; ++reg) li[reg] = __shfl(myinv, lkg*4 + reg);
#pragma unroll
    for (int reg = 0; reg < 4; ++reg) {
      const int row = q0w + qr*16 + lkg*4 + reg;
      bf16* dst = attnA + ((size_t)(b*LL + row)) * MODEL + h * HDIM;
#pragma unroll
      for (int db = 0; db < 8; ++db)
        dst[db*16 + lr] = __float2bfloat16(oacc[qr][db][reg] * li[reg]);
    }
  }
}

// ---------------- launch ----------------
extern "C" void kernel_launch(void* const* d_in, const int* in_sizes, int n_in,
                              void* d_out, int out_size, void* d_ws, size_t ws_size,
                              hipStream_t stream)
{
  const float* x    = (const float*)d_in[0];
  const float* cosT = (const float*)d_in[1];
  const float* sinT = (const float*)d_in[2];
  const float* Wqkv = (const float*)d_in[3];
  const float* Wc   = (const float*)d_in[4];
  const float* bc   = (const float*)d_in[5];
  float* out = (float*)d_out;

  // workspace layout (bytes):
  //   x16    @ 0         : 16,777,216   (reused as attnA later)
  //   WqkvT  @ 16777216  : 25,165,824
  //   WcT    @ 41943040  :  8,388,608
  //   Qb     @ 50331648  : 16,777,216
  //   Kb     @ 67108864  : 16,777,216
  //   VTb    @ 83886080  : 16,777,216   -> total 100,663,296 B
  if (ws_size < 100663296u) return;
  char* w = (char*)d_ws;
  bf16* x16   = (bf16*)(w);
  bf16* WqkvT = (bf16*)(w + (size_t)16777216);
  bf16* WcT   = (bf16*)(w + (size_t)41943040);
  bf16* Qb    = (bf16*)(w + (size_t)50331648);
  bf16* Kb    = (bf16*)(w + (size_t)67108864);
  bf16* VTb   = (bf16*)(w + (size_t)83886080);
  bf16* attnA = x16;   // overlay: x16 dead after GEMM1

  // allow dynamic LDS (idempotent; not a stream op -> capture-safe)
  hipFuncSetAttribute(reinterpret_cast<const void*>(&k_gemmP<1>),
                      hipFuncAttributeMaxDynamicSharedMemorySize, 49152);
  hipFuncSetAttribute(reinterpret_cast<const void*>(&k_gemmP<2>),
                      hipFuncAttributeMaxDynamicSharedMemorySize, 49152);
  hipFuncSetAttribute(reinterpret_cast<const void*>(&k_attn),
                      hipFuncAttributeMaxDynamicSharedMemorySize, 108544);

  k_cvt<<<(MTOT*MODEL/4 + 255)/256, 256, 0, stream>>>(x, x16, MTOT*MODEL/4);
  k_transpose<<<dim3(N1/32,    MODEL/32), 256, 0, stream>>>(Wqkv, WqkvT, MODEL, N1);
  k_transpose<<<dim3(MODEL/32, MODEL/32), 256, 0, stream>>>(Wc,   WcT,   MODEL, MODEL);

  // grid 48*32 = 1536 blocks (3 blocks/CU -> 2 exact rounds of 768)
  k_gemmP<1><<<(N1/128)*(MTOT/128), 512, 49152, stream>>>(
      x16, WqkvT, MTOT, N1, MODEL,
      nullptr, nullptr, Qb, Kb, VTb, cosT, sinT);

  // grid 8*32 = 256 blocks, 8 waves each, paired q-tiles share staged KV
  k_attn<<<dim3(8, BB*NHEAD), 512, 108544, stream>>>(Qb, Kb, VTb, attnA);

  // grid 16*32 = 512 blocks
  k_gemmP<2><<<(MODEL/128)*(MTOT/128), 512, 49152, stream>>>(
      attnA, WcT, MTOT, MODEL, MODEL,
      out, bc, nullptr, nullptr, nullptr, nullptr, nullptr);
}

// Round 23
// 283.850 us; speedup vs baseline: 1.0133x; 1.0124x over previous
//
#include <hip/hip_runtime.h>
#include <hip/hip_bf16.h>

#define MODEL 2048
#define NHEAD 16
#define HDIM  128
#define BB    2
#define LL    2048
#define N1    (3*MODEL)      // 6144
#define MTOT  (BB*LL)        // 4096

typedef __hip_bfloat16 bf16;
typedef __attribute__((ext_vector_type(8))) short bf16x8;
typedef __attribute__((ext_vector_type(4))) float f32x4;

static __device__ __forceinline__ f32x4 mfma16(bf16x8 a, bf16x8 b, f32x4 c) {
  return __builtin_amdgcn_mfma_f32_16x16x32_bf16(a, b, c, 0, 0, 0);
}

// async global->LDS DMA, 16B per lane; LDS base wave-uniform, dest linear
static __device__ __forceinline__ void gl_lds16(const void* g, void* l) {
  __builtin_amdgcn_global_load_lds(
      (const __attribute__((address_space(1))) unsigned int*)g,
      (__attribute__((address_space(3))) unsigned int*)l, 16, 0, 0);
}

static __device__ __forceinline__ unsigned bfu(float x) {
  bf16 b = __float2bfloat16(x);
  return (unsigned)*reinterpret_cast<unsigned short*>(&b);
}

#define BARRIER __builtin_amdgcn_s_barrier()
#define SCHED0  __builtin_amdgcn_sched_barrier(0)
#define PRIO1 __builtin_amdgcn_s_setprio(1)
#define PRIO0 __builtin_amdgcn_s_setprio(0)

// ---------------- fused prep: cvt(x) + transpose(Wqkv) + transpose(Wc) ------
// One dispatch, 1-D grid partitioned by block range (each sub-job's per-block
// body is byte-identical to the r22 kernels; branch is block-uniform):
//   blocks [0, 8192)        : x f32 -> bf16 (float4 per thread)
//   blocks [8192, 20480)    : Wqkv [2048][6144] -> WqkvT [6144][2048] bf16
//   blocks [20480, 24576)   : Wc   [2048][2048] -> WcT   [2048][2048] bf16
// Co-schedules the streaming cvt with the LDS-round-trip transposes ->
// fewer launch gaps, better BW saturation.
__global__ __launch_bounds__(256)
void k_prep(const float* __restrict__ x, bf16* __restrict__ x16,
            const float* __restrict__ Wqkv, bf16* __restrict__ WqkvT,
            const float* __restrict__ Wc, bf16* __restrict__ WcT)
{
  __shared__ float t[32][33];
  const int bid = blockIdx.x;

  if (bid < 8192) {
    const int i = bid * 256 + threadIdx.x;       // 8192*256 = 2,097,152 = n4
    float4 v = ((const float4*)x)[i];
    bf16* o = x16 + (size_t)i * 4;
    o[0] = __float2bfloat16(v.x);
    o[1] = __float2bfloat16(v.y);
    o[2] = __float2bfloat16(v.z);
    o[3] = __float2bfloat16(v.w);
    return;
  }

  const float* in; bf16* outp; int C, bx, by;
  if (bid < 20480) {
    const int b2 = bid - 8192;                   // Wqkv: 192 x 64 blocks
    in = Wqkv; outp = WqkvT; C = N1;
    bx = b2 % 192; by = b2 / 192;
  } else {
    const int b3 = bid - 20480;                  // Wc: 64 x 64 blocks
    in = Wc; outp = WcT; C = MODEL;
    bx = b3 % 64; by = b3 / 64;
  }
  const int R = MODEL;
  const int c0 = bx * 32, r0 = by * 32;
  const int tx = threadIdx.x & 31;
  const int ty = threadIdx.x >> 5;   // 0..7
#pragma unroll
  for (int i = 0; i < 4; ++i)
    t[ty + 8*i][tx] = in[(size_t)(r0 + ty + 8*i) * C + c0 + tx];
  __syncthreads();
#pragma unroll
  for (int i = 0; i < 4; ++i)
    outp[(size_t)(c0 + ty + 8*i) * R + r0 + tx] = __float2bfloat16(t[tx][ty + 8*i]);
}

// ====== 128x128 GEMM, BK=32, 3-buffer pipeline, 3 blocks/CU (r16-exact) ======
// r12-proven skeleton: 8 waves 2Mx4N, lockstep tile, distributed staging +
// collective barrier per tile [r8 lesson], mod-3 rotation with depth-2
// staging [r12 safety], slot swizzle [r6, 0-conflict], square XCD chunking
// [r12: per-XCD A panel L2-fits].
// EPI==1: RoPE + scatter Q/K row-major + V^T ; EPI==2: bias + f32 out.
template<int EPI>
__global__ __launch_bounds__(512, 4)
void k_gemmP(const bf16* __restrict__ A, const bf16* __restrict__ BT,
             int M, int N, int K,
             float* __restrict__ Cout, const float* __restrict__ bias,
             bf16* __restrict__ Qb, bf16* __restrict__ Kb, bf16* __restrict__ VTb,
             const float* __restrict__ cosT, const float* __restrict__ sinT)
{
  constexpr int ABUF = 8192;           // one A tile (128 rows x 64B)
  constexpr int BBUF = 8192;
  constexpr int AREG = 3 * ABUF;       // 24576
  extern __shared__ char smem[];       // 49152 B

  const int tid = threadIdx.x;
  const int wid = tid >> 6, lane = tid & 63;
  const int wm = wid >> 2, wn = wid & 3;       // wave grid 2(M) x 4(N)
  const int lr = lane & 15, lkg = lane >> 4;

  // XCD chunk map (bid%8 = XCD): XCD=(mquarter, nhalf) owns an
  // 8 m-tile x (nbx/2) n-tile chunk, m-inner traversal (A panel L2-fits).
  const int nbx = N >> 7;
  const int xcd = blockIdx.x & 7;
  const int i   = blockIdx.x >> 3;
  const int m0 = (((xcd >> 1) << 3) + (i & 7)) << 7;
  const int n0 = ((xcd & 1) * (nbx >> 1) + (i >> 3)) << 7;

  // staging: wave wid owns 16 rows; source slot carries inverse swizzle
  const int scol = ((lane & 3) ^ ((lane >> 3) & 3)) * 8;   // bf16 elems
  const bf16* Asrc = A  + (size_t)(m0 + wid*16 + (lane >> 2)) * K + scol;
  const bf16* Bsrc = BT + (size_t)(n0 + wid*16 + (lane >> 2)) * K + scol;

  auto stageA = [&](int t) {
    gl_lds16(Asrc + t*32, smem + (t % 3)*ABUF + wid*1024);
  };
  auto stageB = [&](int t) {
    gl_lds16(Bsrc + t*32, smem + AREG + (t % 3)*BBUF + wid*1024);
  };

  // ds_read fragment bases (row = 64B, slot XOR-swizzled by row bits 1-2)
  const int slotX = (lkg ^ ((lr >> 1) & 3)) * 16;
  const int aBase = wm*4096 + lr*64 + slotX;   // rows wm*64 + mf*16 + lr
  const int bBase = wn*2048 + lr*64 + slotX;   // rows wn*32 + nf*16 + lr

  const f32x4 vzero = {0.f, 0.f, 0.f, 0.f};
  f32x4 acc[4][2];
#pragma unroll
  for (int ii = 0; ii < 4; ++ii)
#pragma unroll
    for (int j = 0; j < 2; ++j) acc[ii][j] = vzero;

  const int nt = K >> 5;              // K-tiles of 32 (>= 3)

  // prologue: stage tiles 0,1 -> wait until tile 0's 2 loads complete
  stageA(0); stageB(0); stageA(1); stageB(1);
  asm volatile("s_waitcnt vmcnt(2)" ::: "memory");
  SCHED0; BARRIER;

  for (int t = 0; t < nt; ++t) {
    const int bufA = (t % 3) * ABUF;
    const int bufB = AREG + (t % 3) * BBUF;
    const int ts   = (t + 2 < nt) ? t + 2 : nt - 1;   // clamp: same-data dup
    bf16x8 aFr[4], bFr[2];

#pragma unroll
    for (int mf = 0; mf < 4; ++mf)
      aFr[mf] = *(const bf16x8*)(smem + bufA + aBase + mf*1024);
#pragma unroll
    for (int nf = 0; nf < 2; ++nf)
      bFr[nf] = *(const bf16x8*)(smem + bufB + bBase + nf*1024);
    stageA(ts); stageB(ts);

    // no explicit lgkm drain: compiler emits fine-grained lgkmcnt per dep
    PRIO1;
#pragma unroll
    for (int mf = 0; mf < 4; ++mf)
#pragma unroll
      for (int nf = 0; nf < 2; ++nf)
        acc[mf][nf] = mfma16(aFr[mf], bFr[nf], acc[mf][nf]);
    PRIO0;
    // complete tile t+1's loads (only stage(t+2)'s 2 loads stay in flight)
    asm volatile("s_waitcnt vmcnt(2)" ::: "memory");
    SCHED0;
    BARRIER;                          // collective: tile t+1 visible to all
  }

  if constexpr (EPI == 1) {
    const float inv_sqrt_d = 0.08838834764831845f;  // 1/sqrt(128)
#pragma unroll
    for (int nf = 0; nf < 2; ++nf) {
      const int gcb = n0 + wn*32 + nf*16;           // wave-uniform, mult of 16
      const int section = gcb >> 11;                // 0=q 1=k 2=v
      const int cc = (gcb & 2047) + lr;
      const int h = cc >> 7, d = cc & 127;
#pragma unroll
      for (int mf = 0; mf < 4; ++mf) {
#pragma unroll
        for (int reg = 0; reg < 4; ++reg) {
          const int grow = m0 + wm*64 + mf*16 + lkg*4 + reg;
          const int bidx = grow >> 11, lseq = grow & 2047;
          float val = acc[mf][nf][reg];
          if (section < 2) {
            float p = __shfl_xor(val, 1);           // RoPE pair partner
            const int fi = d >> 1;
            float cv = cosT[(size_t)lseq * 64 + fi];
            float sv = sinT[(size_t)lseq * 64 + fi];
            float r = (d & 1) ? fmaf(p, sv, val * cv)
                              : fmaf(val, cv, -p * sv);
            if (section == 0) {
              r *= inv_sqrt_d;
              Qb[((size_t)(bidx*NHEAD + h) * LL + lseq) * HDIM + d] = __float2bfloat16(r);
            } else {
              Kb[((size_t)(bidx*NHEAD + h) * LL + lseq) * HDIM + d] = __float2bfloat16(r);
            }
          } else {
            VTb[((size_t)(bidx*NHEAD + h) * HDIM + d) * LL + lseq] = __float2bfloat16(val);
          }
        }
      }
    }
  } else {
#pragma unroll
    for (int nf = 0; nf < 2; ++nf) {
      const int gcol = n0 + wn*32 + nf*16 + lr;
      const float bv = bias[gcol];
#pragma unroll
      for (int mf = 0; mf < 4; ++mf) {
#pragma unroll
        for (int reg = 0; reg < 4; ++reg) {
          const int grow = m0 + wm*64 + mf*16 + lkg*4 + reg;
          Cout[(size_t)grow * N + gcol] = acc[mf][nf][reg] + bv;
        }
      }
    }
  }
}

// ---------------- flash attention (r22-exact): merged pair + dbuf + T13 -----
__global__ __launch_bounds__(512)
void k_attn(const bf16* __restrict__ Qb, const bf16* __restrict__ Kb,
            const bf16* __restrict__ VTb, bf16* __restrict__ attnA)
{
  extern __shared__ char asmem[];
  // K buf b: asmem + b*17408            ([64][136] bf16)
  // V buf b: asmem + 34816 + b*18432    ([128][72] bf16)
  // Ps:      asmem + 71680              ([8][32][72] bf16)
  bf16* PsB = (bf16*)(asmem + 71680);

  const int bh  = blockIdx.y;
  const int bx  = blockIdx.x;                 // 0..7
  const int tid = threadIdx.x;                // 0..511
  const int wid = tid >> 6, lane = tid & 63;
  const int lr  = lane & 15, lkg = lane >> 4;

  const bf16* Qh = Qb  + (size_t)bh * LL * HDIM;
  const bf16* Kh = Kb  + (size_t)bh * LL * HDIM;
  const bf16* Vh = VTb + (size_t)bh * HDIM * LL;
  const int b = bh >> 4, h = bh & 15;
  const f32x4 vzero = {0.f, 0.f, 0.f, 0.f};

  const int qt  = (wid < 4) ? (15 - bx) : bx;   // heavy tile on waves 0-3
  const int q0w = qt * 128 + (wid & 3) * 32;

  bf16x8 qf[2][4];
#pragma unroll
  for (int qr = 0; qr < 2; ++qr)
#pragma unroll
    for (int kk = 0; kk < 4; ++kk)
      qf[qr][kk] = *(const bf16x8*)(Qh + (size_t)(q0w + qr*16 + lr) * HDIM + kk*32 + lkg*8);

  f32x4 oacc[2][8];
#pragma unroll
  for (int qr = 0; qr < 2; ++qr)
#pragma unroll
    for (int db = 0; db < 8; ++db) oacc[qr][db] = vzero;
  float ml[2] = {-INFINITY, -INFINITY};
  float ll[2] = {0.f, 0.f};

  const int NT = (15 - bx) * 2 + 2;   // heavy tile's kv-tile count (max)

  // prologue: tile 0 into regs
  bf16x8 kpre[2], vpre[2];
#pragma unroll
  for (int j = 0; j < 2; ++j) {
    const int c = j*512 + tid;
    kpre[j] = *(const bf16x8*)(Kh + (size_t)(c >> 4) * HDIM + (c & 15) * 8);
    vpre[j] = *(const bf16x8*)(Vh + (size_t)(c >> 3) * LL + (c & 7) * 8);
  }

  for (int kt = 0; kt < NT; ++kt) {
    const int kbase = kt * 64;
    bf16* KsB = (bf16*)(asmem + (kt & 1) * 17408);
    bf16* VsB = (bf16*)(asmem + 34816 + (kt & 1) * 18432);

    // write tile kt into buf kt&1 (WAR-safe: buf's readers were iter kt-2,
    // all waves crossed barrier(kt-1) before this point)
#pragma unroll
    for (int j = 0; j < 2; ++j) {
      const int c = j*512 + tid;
      *(bf16x8*)&KsB[(c >> 4) * 136 + (c & 15) * 8] = kpre[j];
      *(bf16x8*)&VsB[(c >> 3) * 72  + (c & 7)  * 8] = vpre[j];
    }
    // issue next-tile global loads (consumed after next barrier)
    if (kt + 1 < NT) {
#pragma unroll
      for (int j = 0; j < 2; ++j) {
        const int c = j*512 + tid;
        kpre[j] = *(const bf16x8*)(Kh + (size_t)((kt+1)*64 + (c >> 4)) * HDIM + (c & 15) * 8);
        vpre[j] = *(const bf16x8*)(Vh + (size_t)(c >> 3) * LL + (kt+1)*64 + (c & 7) * 8);
      }
    }
    __syncthreads();                  // single barrier: publish + guard

    if (kbase <= q0w + 31) {
      f32x4 s2[2][4];
#pragma unroll
      for (int qr = 0; qr < 2; ++qr)
#pragma unroll
        for (int c = 0; c < 4; ++c) s2[qr][c] = vzero;
#pragma unroll
      for (int c = 0; c < 4; ++c) {
        bf16x8 kf[4];
#pragma unroll
        for (int kk = 0; kk < 4; ++kk)
          kf[kk] = *(const bf16x8*)&KsB[(c*16 + lr) * 136 + kk*32 + lkg*8];
#pragma unroll
        for (int qr = 0; qr < 2; ++qr)
#pragma unroll
          for (int kk = 0; kk < 4; ++kk)
            s2[qr][c] = mfma16(kf[kk], qf[qr][kk], s2[qr][c]);
      }
#pragma unroll
      for (int qr = 0; qr < 2; ++qr) {
        const int qrow = q0w + qr*16 + lr;
        float pv[4][4];
#pragma unroll
        for (int c = 0; c < 4; ++c)
#pragma unroll
          for (int reg = 0; reg < 4; ++reg) {
            const int kv = kbase + c*16 + lkg*4 + reg;
            pv[c][reg] = (kv <= qrow) ? s2[qr][c][reg] : -INFINITY;
          }
        float tm = pv[0][0];
#pragma unroll
        for (int c = 0; c < 4; ++c)
#pragma unroll
          for (int reg = 0; reg < 4; ++reg)
            if (c || reg) tm = fmaxf(tm, pv[c][reg]);
        tm = fmaxf(tm, __shfl_xor(tm, 16));
        tm = fmaxf(tm, __shfl_xor(tm, 32));
        // T13 defer-max: if the new tile max doesn't exceed ml+8 on ANY
        // lane, keep ml (P bounded by e^8) and skip the rescale entirely.
        if (__all(tm <= ml[qr] + 8.0f)) {
          float rs = 0.f;
#pragma unroll
          for (int c = 0; c < 4; ++c)
#pragma unroll
            for (int reg = 0; reg < 4; ++reg) {
              pv[c][reg] = __expf(pv[c][reg] - ml[qr]);
              rs += pv[c][reg];
            }
          rs += __shfl_xor(rs, 16);
          rs += __shfl_xor(rs, 32);
          ll[qr] += rs;
        } else {
          const float mnew = fmaxf(ml[qr], tm);
          const float scl  = __expf(ml[qr] - mnew);
          ml[qr] = mnew;
          float rs = 0.f;
#pragma unroll
          for (int c = 0; c < 4; ++c)
#pragma unroll
            for (int reg = 0; reg < 4; ++reg) {
              pv[c][reg] = __expf(pv[c][reg] - mnew);
              rs += pv[c][reg];
            }
          rs += __shfl_xor(rs, 16);
          rs += __shfl_xor(rs, 32);
          ll[qr] = ll[qr] * scl + rs;
          float sr[4];
#pragma unroll
          for (int reg = 0; reg < 4; ++reg) sr[reg] = __shfl(scl, lkg*4 + reg);
#pragma unroll
          for (int db = 0; db < 8; ++db) {
            oacc[qr][db][0] *= sr[0]; oacc[qr][db][1] *= sr[1];
            oacc[qr][db][2] *= sr[2]; oacc[qr][db][3] *= sr[3];
          }
        }
#pragma unroll
        for (int c = 0; c < 4; ++c) {
          unsigned lo = bfu(pv[c][0]) | (bfu(pv[c][1]) << 16);
          unsigned hi = bfu(pv[c][2]) | (bfu(pv[c][3]) << 16);
          *(uint2*)&PsB[(wid*32 + qr*16 + lr) * 72 + c*16 + lkg*4] = make_uint2(lo, hi);
        }
      }
      asm volatile("s_waitcnt lgkmcnt(0)" ::: "memory");
      __builtin_amdgcn_sched_barrier(0);
      bf16x8 pf[2][2];
#pragma unroll
      for (int qr = 0; qr < 2; ++qr)
#pragma unroll
        for (int k2 = 0; k2 < 2; ++k2)
          pf[qr][k2] = *(const bf16x8*)&PsB[(wid*32 + qr*16 + lr) * 72 + k2*32 + lkg*8];
#pragma unroll
      for (int db = 0; db < 8; ++db) {
        bf16x8 vf0 = *(const bf16x8*)&VsB[(db*16 + lr) * 72 + lkg*8];
        bf16x8 vf1 = *(const bf16x8*)&VsB[(db*16 + lr) * 72 + 32 + lkg*8];
#pragma unroll
        for (int qr = 0; qr < 2; ++qr) {
          oacc[qr][db] = mfma16(pf[qr][0], vf0, oacc[qr][db]);
          oacc[qr][db] = mfma16(pf[qr][1], vf1, oacc[qr][db]);
        }
      }
    }
  }

#pragma unroll
  for (int qr = 0; qr < 2; ++qr) {
    const float myinv = 1.0f / ll[qr];
    float li[4];
#pragma unroll
    for (int reg = 0; reg < 4; ++reg) li[reg] = __shfl(myinv, lkg*4 + reg);
#pragma unroll
    for (int reg = 0; reg < 4; ++reg) {
      const int row = q0w + qr*16 + lkg*4 + reg;
      bf16* dst = attnA + ((size_t)(b*LL + row)) * MODEL + h * HDIM;
#pragma unroll
      for (int db = 0; db < 8; ++db)
        dst[db*16 + lr] = __float2bfloat16(oacc[qr][db][reg] * li[reg]);
    }
  }
}

// ---------------- launch ----------------
extern "C" void kernel_launch(void* const* d_in, const int* in_sizes, int n_in,
                              void* d_out, int out_size, void* d_ws, size_t ws_size,
                              hipStream_t stream)
{
  const float* x    = (const float*)d_in[0];
  const float* cosT = (const float*)d_in[1];
  const float* sinT = (const float*)d_in[2];
  const float* Wqkv = (const float*)d_in[3];
  const float* Wc   = (const float*)d_in[4];
  const float* bc   = (const float*)d_in[5];
  float* out = (float*)d_out;

  // workspace layout (bytes):
  //   x16    @ 0         : 16,777,216   (reused as attnA later)
  //   WqkvT  @ 16777216  : 25,165,824
  //   WcT    @ 41943040  :  8,388,608
  //   Qb     @ 50331648  : 16,777,216
  //   Kb     @ 67108864  : 16,777,216
  //   VTb    @ 83886080  : 16,777,216   -> total 100,663,296 B
  if (ws_size < 100663296u) return;
  char* w = (char*)d_ws;
  bf16* x16   = (bf16*)(w);
  bf16* WqkvT = (bf16*)(w + (size_t)16777216);
  bf16* WcT   = (bf16*)(w + (size_t)41943040);
  bf16* Qb    = (bf16*)(w + (size_t)50331648);
  bf16* Kb    = (bf16*)(w + (size_t)67108864);
  bf16* VTb   = (bf16*)(w + (size_t)83886080);
  bf16* attnA = x16;   // overlay: x16 dead after GEMM1

  // allow dynamic LDS (idempotent; not a stream op -> capture-safe)
  hipFuncSetAttribute(reinterpret_cast<const void*>(&k_gemmP<1>),
                      hipFuncAttributeMaxDynamicSharedMemorySize, 49152);
  hipFuncSetAttribute(reinterpret_cast<const void*>(&k_gemmP<2>),
                      hipFuncAttributeMaxDynamicSharedMemorySize, 49152);
  hipFuncSetAttribute(reinterpret_cast<const void*>(&k_attn),
                      hipFuncAttributeMaxDynamicSharedMemorySize, 108544);

  // single fused prep dispatch: cvt (8192) + WqkvT (12288) + WcT (4096)
  k_prep<<<24576, 256, 0, stream>>>(x, x16, Wqkv, WqkvT, Wc, WcT);

  // grid 48*32 = 1536 blocks (3 blocks/CU -> 2 exact rounds of 768)
  k_gemmP<1><<<(N1/128)*(MTOT/128), 512, 49152, stream>>>(
      x16, WqkvT, MTOT, N1, MODEL,
      nullptr, nullptr, Qb, Kb, VTb, cosT, sinT);

  // grid 8*32 = 256 blocks, 8 waves each, paired q-tiles share staged KV
  k_attn<<<dim3(8, BB*NHEAD), 512, 108544, stream>>>(Qb, Kb, VTb, attnA);

  // grid 16*32 = 512 blocks
  k_gemmP<2><<<(MODEL/128)*(MTOT/128), 512, 49152, stream>>>(
      attnA, WcT, MTOT, MODEL, MODEL,
      out, bc, nullptr, nullptr, nullptr, nullptr, nullptr);
}

// Round 24
// 281.606 us; speedup vs baseline: 1.0213x; 1.0080x over previous
//
#include <hip/hip_runtime.h>
#include <hip/hip_bf16.h>

#define MODEL 2048
#define NHEAD 16
#define HDIM  128
#define BB    2
#define LL    2048
#define N1    (3*MODEL)      // 6144
#define MTOT  (BB*LL)        // 4096

typedef __hip_bfloat16 bf16;
typedef __attribute__((ext_vector_type(8))) short bf16x8;
typedef __attribute__((ext_vector_type(4))) float f32x4;

static __device__ __forceinline__ f32x4 mfma16(bf16x8 a, bf16x8 b, f32x4 c) {
  return __builtin_amdgcn_mfma_f32_16x16x32_bf16(a, b, c, 0, 0, 0);
}

// async global->LDS DMA, 16B per lane; LDS base wave-uniform, dest linear
static __device__ __forceinline__ void gl_lds16(const void* g, void* l) {
  __builtin_amdgcn_global_load_lds(
      (const __attribute__((address_space(1))) unsigned int*)g,
      (__attribute__((address_space(3))) unsigned int*)l, 16, 0, 0);
}

static __device__ __forceinline__ unsigned bfu(float x) {
  bf16 b = __float2bfloat16(x);
  return (unsigned)*reinterpret_cast<unsigned short*>(&b);
}

#define BARRIER __builtin_amdgcn_s_barrier()
#define SCHED0  __builtin_amdgcn_sched_barrier(0)
#define PRIO1 __builtin_amdgcn_s_setprio(1)
#define PRIO0 __builtin_amdgcn_s_setprio(0)

// ---------------- fused prep: cvt(x) + transpose(Wqkv) + transpose(Wc) ------
// One dispatch, 1-D grid partitioned by block range (r23-proven):
//   blocks [0, 8192)        : x f32 -> bf16 (float4 per thread)
//   blocks [8192, 20480)    : Wqkv [2048][6144] -> WqkvT [6144][2048] bf16
//   blocks [20480, 24576)   : Wc   [2048][2048] -> WcT   [2048][2048] bf16
__global__ __launch_bounds__(256)
void k_prep(const float* __restrict__ x, bf16* __restrict__ x16,
            const float* __restrict__ Wqkv, bf16* __restrict__ WqkvT,
            const float* __restrict__ Wc, bf16* __restrict__ WcT)
{
  __shared__ float t[32][33];
  const int bid = blockIdx.x;

  if (bid < 8192) {
    const int i = bid * 256 + threadIdx.x;       // 8192*256 = 2,097,152 = n4
    float4 v = ((const float4*)x)[i];
    bf16* o = x16 + (size_t)i * 4;
    o[0] = __float2bfloat16(v.x);
    o[1] = __float2bfloat16(v.y);
    o[2] = __float2bfloat16(v.z);
    o[3] = __float2bfloat16(v.w);
    return;
  }

  const float* in; bf16* outp; int C, bx, by;
  if (bid < 20480) {
    const int b2 = bid - 8192;                   // Wqkv: 192 x 64 blocks
    in = Wqkv; outp = WqkvT; C = N1;
    bx = b2 % 192; by = b2 / 192;
  } else {
    const int b3 = bid - 20480;                  // Wc: 64 x 64 blocks
    in = Wc; outp = WcT; C = MODEL;
    bx = b3 % 64; by = b3 / 64;
  }
  const int R = MODEL;
  const int c0 = bx * 32, r0 = by * 32;
  const int tx = threadIdx.x & 31;
  const int ty = threadIdx.x >> 5;   // 0..7
#pragma unroll
  for (int i = 0; i < 4; ++i)
    t[ty + 8*i][tx] = in[(size_t)(r0 + ty + 8*i) * C + c0 + tx];
  __syncthreads();
#pragma unroll
  for (int i = 0; i < 4; ++i)
    outp[(size_t)(c0 + ty + 8*i) * R + r0 + tx] = __float2bfloat16(t[tx][ty + 8*i]);
}

// ====== 128x128 GEMM, BK=32, 3-buffer pipeline (r16 inner loop) ======
// r12-proven skeleton: 8 waves 2Mx4N, lockstep tile, distributed staging +
// collective barrier per tile [r8 lesson], mod-3 rotation with depth-2
// staging [r12 safety], slot swizzle [r6, 0-conflict], square XCD chunking
// [r12: per-XCD A panel L2-fits].
// r24: g1 launched with 64KB dynamic LDS (uses 48KB) to force 2 blocks/CU --
// the g1-vs-g2 cross-kernel arithmetic (1013 vs 845 cy/tile, same kernel)
// shows 3-way LDS-pipe sharing oversubscribes; 1536 blocks = 3 rounds of 512.
// EPI==1: RoPE + scatter Q/K row-major + V^T ; EPI==2: bias + f32 out.
template<int EPI>
__global__ __launch_bounds__(512, 4)
void k_gemmP(const bf16* __restrict__ A, const bf16* __restrict__ BT,
             int M, int N, int K,
             float* __restrict__ Cout, const float* __restrict__ bias,
             bf16* __restrict__ Qb, bf16* __restrict__ Kb, bf16* __restrict__ VTb,
             const float* __restrict__ cosT, const float* __restrict__ sinT)
{
  constexpr int ABUF = 8192;           // one A tile (128 rows x 64B)
  constexpr int BBUF = 8192;
  constexpr int AREG = 3 * ABUF;       // 24576
  extern __shared__ char smem[];       // 49152 B used (g1 requests 64KB pad)

  const int tid = threadIdx.x;
  const int wid = tid >> 6, lane = tid & 63;
  const int wm = wid >> 2, wn = wid & 3;       // wave grid 2(M) x 4(N)
  const int lr = lane & 15, lkg = lane >> 4;

  // XCD chunk map (bid%8 = XCD): XCD=(mquarter, nhalf) owns an
  // 8 m-tile x (nbx/2) n-tile chunk, m-inner traversal (A panel L2-fits).
  const int nbx = N >> 7;
  const int xcd = blockIdx.x & 7;
  const int i   = blockIdx.x >> 3;
  const int m0 = (((xcd >> 1) << 3) + (i & 7)) << 7;
  const int n0 = ((xcd & 1) * (nbx >> 1) + (i >> 3)) << 7;

  // staging: wave wid owns 16 rows; source slot carries inverse swizzle
  const int scol = ((lane & 3) ^ ((lane >> 3) & 3)) * 8;   // bf16 elems
  const bf16* Asrc = A  + (size_t)(m0 + wid*16 + (lane >> 2)) * K + scol;
  const bf16* Bsrc = BT + (size_t)(n0 + wid*16 + (lane >> 2)) * K + scol;

  auto stageA = [&](int t) {
    gl_lds16(Asrc + t*32, smem + (t % 3)*ABUF + wid*1024);
  };
  auto stageB = [&](int t) {
    gl_lds16(Bsrc + t*32, smem + AREG + (t % 3)*BBUF + wid*1024);
  };

  // ds_read fragment bases (row = 64B, slot XOR-swizzled by row bits 1-2)
  const int slotX = (lkg ^ ((lr >> 1) & 3)) * 16;
  const int aBase = wm*4096 + lr*64 + slotX;   // rows wm*64 + mf*16 + lr
  const int bBase = wn*2048 + lr*64 + slotX;   // rows wn*32 + nf*16 + lr

  const f32x4 vzero = {0.f, 0.f, 0.f, 0.f};
  f32x4 acc[4][2];
#pragma unroll
  for (int ii = 0; ii < 4; ++ii)
#pragma unroll
    for (int j = 0; j < 2; ++j) acc[ii][j] = vzero;

  const int nt = K >> 5;              // K-tiles of 32 (>= 3)

  // prologue: stage tiles 0,1 -> wait until tile 0's 2 loads complete
  stageA(0); stageB(0); stageA(1); stageB(1);
  asm volatile("s_waitcnt vmcnt(2)" ::: "memory");
  SCHED0; BARRIER;

  for (int t = 0; t < nt; ++t) {
    const int bufA = (t % 3) * ABUF;
    const int bufB = AREG + (t % 3) * BBUF;
    const int ts   = (t + 2 < nt) ? t + 2 : nt - 1;   // clamp: same-data dup
    bf16x8 aFr[4], bFr[2];

#pragma unroll
    for (int mf = 0; mf < 4; ++mf)
      aFr[mf] = *(const bf16x8*)(smem + bufA + aBase + mf*1024);
#pragma unroll
    for (int nf = 0; nf < 2; ++nf)
      bFr[nf] = *(const bf16x8*)(smem + bufB + bBase + nf*1024);
    stageA(ts); stageB(ts);

    // no explicit lgkm drain: compiler emits fine-grained lgkmcnt per dep
    PRIO1;
#pragma unroll
    for (int mf = 0; mf < 4; ++mf)
#pragma unroll
      for (int nf = 0; nf < 2; ++nf)
        acc[mf][nf] = mfma16(aFr[mf], bFr[nf], acc[mf][nf]);
    PRIO0;
    // complete tile t+1's loads (only stage(t+2)'s 2 loads stay in flight)
    asm volatile("s_waitcnt vmcnt(2)" ::: "memory");
    SCHED0;
    BARRIER;                          // collective: tile t+1 visible to all
  }

  if constexpr (EPI == 1) {
    const float inv_sqrt_d = 0.08838834764831845f;  // 1/sqrt(128)
#pragma unroll
    for (int nf = 0; nf < 2; ++nf) {
      const int gcb = n0 + wn*32 + nf*16;           // wave-uniform, mult of 16
      const int section = gcb >> 11;                // 0=q 1=k 2=v
      const int cc = (gcb & 2047) + lr;
      const int h = cc >> 7, d = cc & 127;
#pragma unroll
      for (int mf = 0; mf < 4; ++mf) {
#pragma unroll
        for (int reg = 0; reg < 4; ++reg) {
          const int grow = m0 + wm*64 + mf*16 + lkg*4 + reg;
          const int bidx = grow >> 11, lseq = grow & 2047;
          float val = acc[mf][nf][reg];
          if (section < 2) {
            float p = __shfl_xor(val, 1);           // RoPE pair partner
            const int fi = d >> 1;
            float cv = cosT[(size_t)lseq * 64 + fi];
            float sv = sinT[(size_t)lseq * 64 + fi];
            float r = (d & 1) ? fmaf(p, sv, val * cv)
                              : fmaf(val, cv, -p * sv);
            if (section == 0) {
              r *= inv_sqrt_d;
              Qb[((size_t)(bidx*NHEAD + h) * LL + lseq) * HDIM + d] = __float2bfloat16(r);
            } else {
              Kb[((size_t)(bidx*NHEAD + h) * LL + lseq) * HDIM + d] = __float2bfloat16(r);
            }
          } else {
            VTb[((size_t)(bidx*NHEAD + h) * HDIM + d) * LL + lseq] = __float2bfloat16(val);
          }
        }
      }
    }
  } else {
#pragma unroll
    for (int nf = 0; nf < 2; ++nf) {
      const int gcol = n0 + wn*32 + nf*16 + lr;
      const float bv = bias[gcol];
#pragma unroll
      for (int mf = 0; mf < 4; ++mf) {
#pragma unroll
        for (int reg = 0; reg < 4; ++reg) {
          const int grow = m0 + wm*64 + mf*16 + lkg*4 + reg;
          Cout[(size_t)grow * N + gcol] = acc[mf][nf][reg] + bv;
        }
      }
    }
  }
}

// ---------------- flash attention (r22-exact): merged pair + dbuf + T13 -----
__global__ __launch_bounds__(512)
void k_attn(const bf16* __restrict__ Qb, const bf16* __restrict__ Kb,
            const bf16* __restrict__ VTb, bf16* __restrict__ attnA)
{
  extern __shared__ char asmem[];
  // K buf b: asmem + b*17408            ([64][136] bf16)
  // V buf b: asmem + 34816 + b*18432    ([128][72] bf16)
  // Ps:      asmem + 71680              ([8][32][72] bf16)
  bf16* PsB = (bf16*)(asmem + 71680);

  const int bh  = blockIdx.y;
  const int bx  = blockIdx.x;                 // 0..7
  const int tid = threadIdx.x;                // 0..511
  const int wid = tid >> 6, lane = tid & 63;
  const int lr  = lane & 15, lkg = lane >> 4;

  const bf16* Qh = Qb  + (size_t)bh * LL * HDIM;
  const bf16* Kh = Kb  + (size_t)bh * LL * HDIM;
  const bf16* Vh = VTb + (size_t)bh * HDIM * LL;
  const int b = bh >> 4, h = bh & 15;
  const f32x4 vzero = {0.f, 0.f, 0.f, 0.f};

  const int qt  = (wid < 4) ? (15 - bx) : bx;   // heavy tile on waves 0-3
  const int q0w = qt * 128 + (wid & 3) * 32;

  bf16x8 qf[2][4];
#pragma unroll
  for (int qr = 0; qr < 2; ++qr)
#pragma unroll
    for (int kk = 0; kk < 4; ++kk)
      qf[qr][kk] = *(const bf16x8*)(Qh + (size_t)(q0w + qr*16 + lr) * HDIM + kk*32 + lkg*8);

  f32x4 oacc[2][8];
#pragma unroll
  for (int qr = 0; qr < 2; ++qr)
#pragma unroll
    for (int db = 0; db < 8; ++db) oacc[qr][db] = vzero;
  float ml[2] = {-INFINITY, -INFINITY};
  float ll[2] = {0.f, 0.f};

  const int NT = (15 - bx) * 2 + 2;   // heavy tile's kv-tile count (max)

  // prologue: tile 0 into regs
  bf16x8 kpre[2], vpre[2];
#pragma unroll
  for (int j = 0; j < 2; ++j) {
    const int c = j*512 + tid;
    kpre[j] = *(const bf16x8*)(Kh + (size_t)(c >> 4) * HDIM + (c & 15) * 8);
    vpre[j] = *(const bf16x8*)(Vh + (size_t)(c >> 3) * LL + (c & 7) * 8);
  }

  for (int kt = 0; kt < NT; ++kt) {
    const int kbase = kt * 64;
    bf16* KsB = (bf16*)(asmem + (kt & 1) * 17408);
    bf16* VsB = (bf16*)(asmem + 34816 + (kt & 1) * 18432);

    // write tile kt into buf kt&1 (WAR-safe: buf's readers were iter kt-2,
    // all waves crossed barrier(kt-1) before this point)
#pragma unroll
    for (int j = 0; j < 2; ++j) {
      const int c = j*512 + tid;
      *(bf16x8*)&KsB[(c >> 4) * 136 + (c & 15) * 8] = kpre[j];
      *(bf16x8*)&VsB[(c >> 3) * 72  + (c & 7)  * 8] = vpre[j];
    }
    // issue next-tile global loads (consumed after next barrier)
    if (kt + 1 < NT) {
#pragma unroll
      for (int j = 0; j < 2; ++j) {
        const int c = j*512 + tid;
        kpre[j] = *(const bf16x8*)(Kh + (size_t)((kt+1)*64 + (c >> 4)) * HDIM + (c & 15) * 8);
        vpre[j] = *(const bf16x8*)(Vh + (size_t)(c >> 3) * LL + (kt+1)*64 + (c & 7) * 8);
      }
    }
    __syncthreads();                  // single barrier: publish + guard

    if (kbase <= q0w + 31) {
      f32x4 s2[2][4];
#pragma unroll
      for (int qr = 0; qr < 2; ++qr)
#pragma unroll
        for (int c = 0; c < 4; ++c) s2[qr][c] = vzero;
#pragma unroll
      for (int c = 0; c < 4; ++c) {
        bf16x8 kf[4];
#pragma unroll
        for (int kk = 0; kk < 4; ++kk)
          kf[kk] = *(const bf16x8*)&KsB[(c*16 + lr) * 136 + kk*32 + lkg*8];
#pragma unroll
        for (int qr = 0; qr < 2; ++qr)
#pragma unroll
          for (int kk = 0; kk < 4; ++kk)
            s2[qr][c] = mfma16(kf[kk], qf[qr][kk], s2[qr][c]);
      }
#pragma unroll
      for (int qr = 0; qr < 2; ++qr) {
        const int qrow = q0w + qr*16 + lr;
        float pv[4][4];
#pragma unroll
        for (int c = 0; c < 4; ++c)
#pragma unroll
          for (int reg = 0; reg < 4; ++reg) {
            const int kv = kbase + c*16 + lkg*4 + reg;
            pv[c][reg] = (kv <= qrow) ? s2[qr][c][reg] : -INFINITY;
          }
        float tm = pv[0][0];
#pragma unroll
        for (int c = 0; c < 4; ++c)
#pragma unroll
          for (int reg = 0; reg < 4; ++reg)
            if (c || reg) tm = fmaxf(tm, pv[c][reg]);
        tm = fmaxf(tm, __shfl_xor(tm, 16));
        tm = fmaxf(tm, __shfl_xor(tm, 32));
        // T13 defer-max: if the new tile max doesn't exceed ml+8 on ANY
        // lane, keep ml (P bounded by e^8) and skip the rescale entirely.
        if (__all(tm <= ml[qr] + 8.0f)) {
          float rs = 0.f;
#pragma unroll
          for (int c = 0; c < 4; ++c)
#pragma unroll
            for (int reg = 0; reg < 4; ++reg) {
              pv[c][reg] = __expf(pv[c][reg] - ml[qr]);
              rs += pv[c][reg];
            }
          rs += __shfl_xor(rs, 16);
          rs += __shfl_xor(rs, 32);
          ll[qr] += rs;
        } else {
          const float mnew = fmaxf(ml[qr], tm);
          const float scl  = __expf(ml[qr] - mnew);
          ml[qr] = mnew;
          float rs = 0.f;
#pragma unroll
          for (int c = 0; c < 4; ++c)
#pragma unroll
            for (int reg = 0; reg < 4; ++reg) {
              pv[c][reg] = __expf(pv[c][reg] - mnew);
              rs += pv[c][reg];
            }
          rs += __shfl_xor(rs, 16);
          rs += __shfl_xor(rs, 32);
          ll[qr] = ll[qr] * scl + rs;
          float sr[4];
#pragma unroll
          for (int reg = 0; reg < 4; ++reg) sr[reg] = __shfl(scl, lkg*4 + reg);
#pragma unroll
          for (int db = 0; db < 8; ++db) {
            oacc[qr][db][0] *= sr[0]; oacc[qr][db][1] *= sr[1];
            oacc[qr][db][2] *= sr[2]; oacc[qr][db][3] *= sr[3];
          }
        }
#pragma unroll
        for (int c = 0; c < 4; ++c) {
          unsigned lo = bfu(pv[c][0]) | (bfu(pv[c][1]) << 16);
          unsigned hi = bfu(pv[c][2]) | (bfu(pv[c][3]) << 16);
          *(uint2*)&PsB[(wid*32 + qr*16 + lr) * 72 + c*16 + lkg*4] = make_uint2(lo, hi);
        }
      }
      asm volatile("s_waitcnt lgkmcnt(0)" ::: "memory");
      __builtin_amdgcn_sched_barrier(0);
      bf16x8 pf[2][2];
#pragma unroll
      for (int qr = 0; qr < 2; ++qr)
#pragma unroll
        for (int k2 = 0; k2 < 2; ++k2)
          pf[qr][k2] = *(const bf16x8*)&PsB[(wid*32 + qr*16 + lr) * 72 + k2*32 + lkg*8];
#pragma unroll
      for (int db = 0; db < 8; ++db) {
        bf16x8 vf0 = *(const bf16x8*)&VsB[(db*16 + lr) * 72 + lkg*8];
        bf16x8 vf1 = *(const bf16x8*)&VsB[(db*16 + lr) * 72 + 32 + lkg*8];
#pragma unroll
        for (int qr = 0; qr < 2; ++qr) {
          oacc[qr][db] = mfma16(pf[qr][0], vf0, oacc[qr][db]);
          oacc[qr][db] = mfma16(pf[qr][1], vf1, oacc[qr][db]);
        }
      }
    }
  }

#pragma unroll
  for (int qr = 0; qr < 2; ++qr) {
    const float myinv = 1.0f / ll[qr];
    float li[4];
#pragma unroll
    for (int reg = 0; reg < 4; ++reg) li[reg] = __shfl(myinv, lkg*4 + reg);
#pragma unroll
    for (int reg = 0; reg < 4; ++reg) {
      const int row = q0w + qr*16 + lkg*4 + reg;
      bf16* dst = attnA + ((size_t)(b*LL + row)) * MODEL + h * HDIM;
#pragma unroll
      for (int db = 0; db < 8; ++db)
        dst[db*16 + lr] = __float2bfloat16(oacc[qr][db][reg] * li[reg]);
    }
  }
}

// ---------------- launch ----------------
extern "C" void kernel_launch(void* const* d_in, const int* in_sizes, int n_in,
                              void* d_out, int out_size, void* d_ws, size_t ws_size,
                              hipStream_t stream)
{
  const float* x    = (const float*)d_in[0];
  const float* cosT = (const float*)d_in[1];
  const float* sinT = (const float*)d_in[2];
  const float* Wqkv = (const float*)d_in[3];
  const float* Wc   = (const float*)d_in[4];
  const float* bc   = (const float*)d_in[5];
  float* out = (float*)d_out;

  // workspace layout (bytes):
  //   x16    @ 0         : 16,777,216   (reused as attnA later)
  //   WqkvT  @ 16777216  : 25,165,824
  //   WcT    @ 41943040  :  8,388,608
  //   Qb     @ 50331648  : 16,777,216
  //   Kb     @ 67108864  : 16,777,216
  //   VTb    @ 83886080  : 16,777,216   -> total 100,663,296 B
  if (ws_size < 100663296u) return;
  char* w = (char*)d_ws;
  bf16* x16   = (bf16*)(w);
  bf16* WqkvT = (bf16*)(w + (size_t)16777216);
  bf16* WcT   = (bf16*)(w + (size_t)41943040);
  bf16* Qb    = (bf16*)(w + (size_t)50331648);
  bf16* Kb    = (bf16*)(w + (size_t)67108864);
  bf16* VTb   = (bf16*)(w + (size_t)83886080);
  bf16* attnA = x16;   // overlay: x16 dead after GEMM1

  // allow dynamic LDS (idempotent; not a stream op -> capture-safe)
  hipFuncSetAttribute(reinterpret_cast<const void*>(&k_gemmP<1>),
                      hipFuncAttributeMaxDynamicSharedMemorySize, 65536);
  hipFuncSetAttribute(reinterpret_cast<const void*>(&k_gemmP<2>),
                      hipFuncAttributeMaxDynamicSharedMemorySize, 49152);
  hipFuncSetAttribute(reinterpret_cast<const void*>(&k_attn),
                      hipFuncAttributeMaxDynamicSharedMemorySize, 108544);

  // single fused prep dispatch: cvt (8192) + WqkvT (12288) + WcT (4096)
  k_prep<<<24576, 256, 0, stream>>>(x, x16, Wqkv, WqkvT, Wc, WcT);

  // grid 1536 blocks; 64KB LDS request (48KB used) -> 2 blocks/CU,
  // 3 exact rounds of 512 (r24 occupancy A/B: g2's 845 cy/tile at 2/CU)
  k_gemmP<1><<<(N1/128)*(MTOT/128), 512, 65536, stream>>>(
      x16, WqkvT, MTOT, N1, MODEL,
      nullptr, nullptr, Qb, Kb, VTb, cosT, sinT);

  // grid 8*32 = 256 blocks, 8 waves each, paired q-tiles share staged KV
  k_attn<<<dim3(8, BB*NHEAD), 512, 108544, stream>>>(Qb, Kb, VTb, attnA);

  // grid 16*32 = 512 blocks (2/CU natural)
  k_gemmP<2><<<(MODEL/128)*(MTOT/128), 512, 49152, stream>>>(
      attnA, WcT, MTOT, MODEL, MODEL,
      out, bc, nullptr, nullptr, nullptr, nullptr, nullptr);
}

// Round 25
// 276.513 us; speedup vs baseline: 1.0402x; 1.0184x over previous
//
#include <hip/hip_runtime.h>
#include <hip/hip_bf16.h>

#define MODEL 2048
#define NHEAD 16
#define HDIM  128
#define BB    2
#define LL    2048
#define N1    (3*MODEL)      // 6144
#define MTOT  (BB*LL)        // 4096

typedef __hip_bfloat16 bf16;
typedef __attribute__((ext_vector_type(8))) short bf16x8;
typedef __attribute__((ext_vector_type(4))) float f32x4;

static __device__ __forceinline__ f32x4 mfma16(bf16x8 a, bf16x8 b, f32x4 c) {
  return __builtin_amdgcn_mfma_f32_16x16x32_bf16(a, b, c, 0, 0, 0);
}

// async global->LDS DMA, 16B per lane; LDS base wave-uniform, dest linear
static __device__ __forceinline__ void gl_lds16(const void* g, void* l) {
  __builtin_amdgcn_global_load_lds(
      (const __attribute__((address_space(1))) unsigned int*)g,
      (__attribute__((address_space(3))) unsigned int*)l, 16, 0, 0);
}

static __device__ __forceinline__ unsigned bfu(float x) {
  bf16 b = __float2bfloat16(x);
  return (unsigned)*reinterpret_cast<unsigned short*>(&b);
}

#define BARRIER __builtin_amdgcn_s_barrier()
#define SCHED0  __builtin_amdgcn_sched_barrier(0)
#define PRIO1 __builtin_amdgcn_s_setprio(1)
#define PRIO0 __builtin_amdgcn_s_setprio(0)

// ---------------- fused prep: cvt(x) + transpose(Wqkv) + transpose(Wc) ------
// One dispatch, 1-D grid partitioned by block range (r23-proven):
//   blocks [0, 8192)        : x f32 -> bf16 (float4 per thread)
//   blocks [8192, 20480)    : Wqkv [2048][6144] -> WqkvT [6144][2048] bf16
//   blocks [20480, 24576)   : Wc   [2048][2048] -> WcT   [2048][2048] bf16
__global__ __launch_bounds__(256)
void k_prep(const float* __restrict__ x, bf16* __restrict__ x16,
            const float* __restrict__ Wqkv, bf16* __restrict__ WqkvT,
            const float* __restrict__ Wc, bf16* __restrict__ WcT)
{
  __shared__ float t[32][33];
  const int bid = blockIdx.x;

  if (bid < 8192) {
    const int i = bid * 256 + threadIdx.x;       // 8192*256 = 2,097,152 = n4
    float4 v = ((const float4*)x)[i];
    bf16* o = x16 + (size_t)i * 4;
    o[0] = __float2bfloat16(v.x);
    o[1] = __float2bfloat16(v.y);
    o[2] = __float2bfloat16(v.z);
    o[3] = __float2bfloat16(v.w);
    return;
  }

  const float* in; bf16* outp; int C, bx, by;
  if (bid < 20480) {
    const int b2 = bid - 8192;                   // Wqkv: 192 x 64 blocks
    in = Wqkv; outp = WqkvT; C = N1;
    bx = b2 % 192; by = b2 / 192;
  } else {
    const int b3 = bid - 20480;                  // Wc: 64 x 64 blocks
    in = Wc; outp = WcT; C = MODEL;
    bx = b3 % 64; by = b3 / 64;
  }
  const int R = MODEL;
  const int c0 = bx * 32, r0 = by * 32;
  const int tx = threadIdx.x & 31;
  const int ty = threadIdx.x >> 5;   // 0..7
#pragma unroll
  for (int i = 0; i < 4; ++i)
    t[ty + 8*i][tx] = in[(size_t)(r0 + ty + 8*i) * C + c0 + tx];
  __syncthreads();
#pragma unroll
  for (int i = 0; i < 4; ++i)
    outp[(size_t)(c0 + ty + 8*i) * R + r0 + tx] = __float2bfloat16(t[tx][ty + 8*i]);
}

// ====== 128x128 GEMM, BK=32, 3-buffer pipeline (r16 inner loop) ======
// r12-proven skeleton: 8 waves 2Mx4N, lockstep tile, distributed staging +
// collective barrier per tile [r8 lesson], mod-3 rotation with depth-2
// staging [r12 safety], slot swizzle [r6, 0-conflict].
// r25 (EPI==1): m-OCTANT XCD chunking -- XCD owns 4 m-tiles (2MB A, truly
// L2-resident; old 8-tile chunk = 4MB = whole L2, thrashed -> A re-fetched
// per n-tile, FETCH 117-133MB vs 40MB compulsory) x all 48 n-tiles, m-inner.
// B panels shared across XCDs via L3. g1 keeps r24's 64KB-pad launch
// (2 blocks/CU -- best scored total).
// EPI==2: r16-exact map (proven 845 cy/tile).
// EPI==1: RoPE + scatter Q/K row-major + V^T ; EPI==2: bias + f32 out.
template<int EPI>
__global__ __launch_bounds__(512, 4)
void k_gemmP(const bf16* __restrict__ A, const bf16* __restrict__ BT,
             int M, int N, int K,
             float* __restrict__ Cout, const float* __restrict__ bias,
             bf16* __restrict__ Qb, bf16* __restrict__ Kb, bf16* __restrict__ VTb,
             const float* __restrict__ cosT, const float* __restrict__ sinT)
{
  constexpr int ABUF = 8192;           // one A tile (128 rows x 64B)
  constexpr int BBUF = 8192;
  constexpr int AREG = 3 * ABUF;       // 24576
  extern __shared__ char smem[];       // 49152 B used (g1 requests 64KB pad)

  const int tid = threadIdx.x;
  const int wid = tid >> 6, lane = tid & 63;
  const int wm = wid >> 2, wn = wid & 3;       // wave grid 2(M) x 4(N)
  const int lr = lane & 15, lkg = lane >> 4;

  // XCD chunk map (bid%8 = XCD)
  const int nbx = N >> 7;
  const int xcd = blockIdx.x & 7;
  const int i   = blockIdx.x >> 3;
  int m0, n0;
  if constexpr (EPI == 1) {
    // m-octant: 4 m-tiles (2MB A, L2-resident) x all n, m-inner
    m0 = ((xcd << 2) + (i & 3)) << 7;
    n0 = (i >> 2) << 7;
  } else {
    m0 = (((xcd >> 1) << 3) + (i & 7)) << 7;
    n0 = ((xcd & 1) * (nbx >> 1) + (i >> 3)) << 7;
  }

  // staging: wave wid owns 16 rows; source slot carries inverse swizzle
  const int scol = ((lane & 3) ^ ((lane >> 3) & 3)) * 8;   // bf16 elems
  const bf16* Asrc = A  + (size_t)(m0 + wid*16 + (lane >> 2)) * K + scol;
  const bf16* Bsrc = BT + (size_t)(n0 + wid*16 + (lane >> 2)) * K + scol;

  auto stageA = [&](int t) {
    gl_lds16(Asrc + t*32, smem + (t % 3)*ABUF + wid*1024);
  };
  auto stageB = [&](int t) {
    gl_lds16(Bsrc + t*32, smem + AREG + (t % 3)*BBUF + wid*1024);
  };

  // ds_read fragment bases (row = 64B, slot XOR-swizzled by row bits 1-2)
  const int slotX = (lkg ^ ((lr >> 1) & 3)) * 16;
  const int aBase = wm*4096 + lr*64 + slotX;   // rows wm*64 + mf*16 + lr
  const int bBase = wn*2048 + lr*64 + slotX;   // rows wn*32 + nf*16 + lr

  const f32x4 vzero = {0.f, 0.f, 0.f, 0.f};
  f32x4 acc[4][2];
#pragma unroll
  for (int ii = 0; ii < 4; ++ii)
#pragma unroll
    for (int j = 0; j < 2; ++j) acc[ii][j] = vzero;

  const int nt = K >> 5;              // K-tiles of 32 (>= 3)

  // prologue: stage tiles 0,1 -> wait until tile 0's 2 loads complete
  stageA(0); stageB(0); stageA(1); stageB(1);
  asm volatile("s_waitcnt vmcnt(2)" ::: "memory");
  SCHED0; BARRIER;

  for (int t = 0; t < nt; ++t) {
    const int bufA = (t % 3) * ABUF;
    const int bufB = AREG + (t % 3) * BBUF;
    const int ts   = (t + 2 < nt) ? t + 2 : nt - 1;   // clamp: same-data dup
    bf16x8 aFr[4], bFr[2];

#pragma unroll
    for (int mf = 0; mf < 4; ++mf)
      aFr[mf] = *(const bf16x8*)(smem + bufA + aBase + mf*1024);
#pragma unroll
    for (int nf = 0; nf < 2; ++nf)
      bFr[nf] = *(const bf16x8*)(smem + bufB + bBase + nf*1024);
    stageA(ts); stageB(ts);

    // no explicit lgkm drain: compiler emits fine-grained lgkmcnt per dep
    PRIO1;
#pragma unroll
    for (int mf = 0; mf < 4; ++mf)
#pragma unroll
      for (int nf = 0; nf < 2; ++nf)
        acc[mf][nf] = mfma16(aFr[mf], bFr[nf], acc[mf][nf]);
    PRIO0;
    // complete tile t+1's loads (only stage(t+2)'s 2 loads stay in flight)
    asm volatile("s_waitcnt vmcnt(2)" ::: "memory");
    SCHED0;
    BARRIER;                          // collective: tile t+1 visible to all
  }

  if constexpr (EPI == 1) {
    const float inv_sqrt_d = 0.08838834764831845f;  // 1/sqrt(128)
#pragma unroll
    for (int nf = 0; nf < 2; ++nf) {
      const int gcb = n0 + wn*32 + nf*16;           // wave-uniform, mult of 16
      const int section = gcb >> 11;                // 0=q 1=k 2=v
      const int cc = (gcb & 2047) + lr;
      const int h = cc >> 7, d = cc & 127;
#pragma unroll
      for (int mf = 0; mf < 4; ++mf) {
#pragma unroll
        for (int reg = 0; reg < 4; ++reg) {
          const int grow = m0 + wm*64 + mf*16 + lkg*4 + reg;
          const int bidx = grow >> 11, lseq = grow & 2047;
          float val = acc[mf][nf][reg];
          if (section < 2) {
            float p = __shfl_xor(val, 1);           // RoPE pair partner
            const int fi = d >> 1;
            float cv = cosT[(size_t)lseq * 64 + fi];
            float sv = sinT[(size_t)lseq * 64 + fi];
            float r = (d & 1) ? fmaf(p, sv, val * cv)
                              : fmaf(val, cv, -p * sv);
            if (section == 0) {
              r *= inv_sqrt_d;
              Qb[((size_t)(bidx*NHEAD + h) * LL + lseq) * HDIM + d] = __float2bfloat16(r);
            } else {
              Kb[((size_t)(bidx*NHEAD + h) * LL + lseq) * HDIM + d] = __float2bfloat16(r);
            }
          } else {
            VTb[((size_t)(bidx*NHEAD + h) * HDIM + d) * LL + lseq] = __float2bfloat16(val);
          }
        }
      }
    }
  } else {
#pragma unroll
    for (int nf = 0; nf < 2; ++nf) {
      const int gcol = n0 + wn*32 + nf*16 + lr;
      const float bv = bias[gcol];
#pragma unroll
      for (int mf = 0; mf < 4; ++mf) {
#pragma unroll
        for (int reg = 0; reg < 4; ++reg) {
          const int grow = m0 + wm*64 + mf*16 + lkg*4 + reg;
          Cout[(size_t)grow * N + gcol] = acc[mf][nf][reg] + bv;
        }
      }
    }
  }
}

// ---------------- flash attention (r22-exact): merged pair + dbuf + T13 -----
__global__ __launch_bounds__(512)
void k_attn(const bf16* __restrict__ Qb, const bf16* __restrict__ Kb,
            const bf16* __restrict__ VTb, bf16* __restrict__ attnA)
{
  extern __shared__ char asmem[];
  // K buf b: asmem + b*17408            ([64][136] bf16)
  // V buf b: asmem + 34816 + b*18432    ([128][72] bf16)
  // Ps:      asmem + 71680              ([8][32][72] bf16)
  bf16* PsB = (bf16*)(asmem + 71680);

  const int bh  = blockIdx.y;
  const int bx  = blockIdx.x;                 // 0..7
  const int tid = threadIdx.x;                // 0..511
  const int wid = tid >> 6, lane = tid & 63;
  const int lr  = lane & 15, lkg = lane >> 4;

  const bf16* Qh = Qb  + (size_t)bh * LL * HDIM;
  const bf16* Kh = Kb  + (size_t)bh * LL * HDIM;
  const bf16* Vh = VTb + (size_t)bh * HDIM * LL;
  const int b = bh >> 4, h = bh & 15;
  const f32x4 vzero = {0.f, 0.f, 0.f, 0.f};

  const int qt  = (wid < 4) ? (15 - bx) : bx;   // heavy tile on waves 0-3
  const int q0w = qt * 128 + (wid & 3) * 32;

  bf16x8 qf[2][4];
#pragma unroll
  for (int qr = 0; qr < 2; ++qr)
#pragma unroll
    for (int kk = 0; kk < 4; ++kk)
      qf[qr][kk] = *(const bf16x8*)(Qh + (size_t)(q0w + qr*16 + lr) * HDIM + kk*32 + lkg*8);

  f32x4 oacc[2][8];
#pragma unroll
  for (int qr = 0; qr < 2; ++qr)
#pragma unroll
    for (int db = 0; db < 8; ++db) oacc[qr][db] = vzero;
  float ml[2] = {-INFINITY, -INFINITY};
  float ll[2] = {0.f, 0.f};

  const int NT = (15 - bx) * 2 + 2;   // heavy tile's kv-tile count (max)

  // prologue: tile 0 into regs
  bf16x8 kpre[2], vpre[2];
#pragma unroll
  for (int j = 0; j < 2; ++j) {
    const int c = j*512 + tid;
    kpre[j] = *(const bf16x8*)(Kh + (size_t)(c >> 4) * HDIM + (c & 15) * 8);
    vpre[j] = *(const bf16x8*)(Vh + (size_t)(c >> 3) * LL + (c & 7) * 8);
  }

  for (int kt = 0; kt < NT; ++kt) {
    const int kbase = kt * 64;
    bf16* KsB = (bf16*)(asmem + (kt & 1) * 17408);
    bf16* VsB = (bf16*)(asmem + 34816 + (kt & 1) * 18432);

    // write tile kt into buf kt&1 (WAR-safe: buf's readers were iter kt-2,
    // all waves crossed barrier(kt-1) before this point)
#pragma unroll
    for (int j = 0; j < 2; ++j) {
      const int c = j*512 + tid;
      *(bf16x8*)&KsB[(c >> 4) * 136 + (c & 15) * 8] = kpre[j];
      *(bf16x8*)&VsB[(c >> 3) * 72  + (c & 7)  * 8] = vpre[j];
    }
    // issue next-tile global loads (consumed after next barrier)
    if (kt + 1 < NT) {
#pragma unroll
      for (int j = 0; j < 2; ++j) {
        const int c = j*512 + tid;
        kpre[j] = *(const bf16x8*)(Kh + (size_t)((kt+1)*64 + (c >> 4)) * HDIM + (c & 15) * 8);
        vpre[j] = *(const bf16x8*)(Vh + (size_t)(c >> 3) * LL + (kt+1)*64 + (c & 7) * 8);
      }
    }
    __syncthreads();                  // single barrier: publish + guard

    if (kbase <= q0w + 31) {
      f32x4 s2[2][4];
#pragma unroll
      for (int qr = 0; qr < 2; ++qr)
#pragma unroll
        for (int c = 0; c < 4; ++c) s2[qr][c] = vzero;
#pragma unroll
      for (int c = 0; c < 4; ++c) {
        bf16x8 kf[4];
#pragma unroll
        for (int kk = 0; kk < 4; ++kk)
          kf[kk] = *(const bf16x8*)&KsB[(c*16 + lr) * 136 + kk*32 + lkg*8];
#pragma unroll
        for (int qr = 0; qr < 2; ++qr)
#pragma unroll
          for (int kk = 0; kk < 4; ++kk)
            s2[qr][c] = mfma16(kf[kk], qf[qr][kk], s2[qr][c]);
      }
#pragma unroll
      for (int qr = 0; qr < 2; ++qr) {
        const int qrow = q0w + qr*16 + lr;
        float pv[4][4];
#pragma unroll
        for (int c = 0; c < 4; ++c)
#pragma unroll
          for (int reg = 0; reg < 4; ++reg) {
            const int kv = kbase + c*16 + lkg*4 + reg;
            pv[c][reg] = (kv <= qrow) ? s2[qr][c][reg] : -INFINITY;
          }
        float tm = pv[0][0];
#pragma unroll
        for (int c = 0; c < 4; ++c)
#pragma unroll
          for (int reg = 0; reg < 4; ++reg)
            if (c || reg) tm = fmaxf(tm, pv[c][reg]);
        tm = fmaxf(tm, __shfl_xor(tm, 16));
        tm = fmaxf(tm, __shfl_xor(tm, 32));
        // T13 defer-max: if the new tile max doesn't exceed ml+8 on ANY
        // lane, keep ml (P bounded by e^8) and skip the rescale entirely.
        if (__all(tm <= ml[qr] + 8.0f)) {
          float rs = 0.f;
#pragma unroll
          for (int c = 0; c < 4; ++c)
#pragma unroll
            for (int reg = 0; reg < 4; ++reg) {
              pv[c][reg] = __expf(pv[c][reg] - ml[qr]);
              rs += pv[c][reg];
            }
          rs += __shfl_xor(rs, 16);
          rs += __shfl_xor(rs, 32);
          ll[qr] += rs;
        } else {
          const float mnew = fmaxf(ml[qr], tm);
          const float scl  = __expf(ml[qr] - mnew);
          ml[qr] = mnew;
          float rs = 0.f;
#pragma unroll
          for (int c = 0; c < 4; ++c)
#pragma unroll
            for (int reg = 0; reg < 4; ++reg) {
              pv[c][reg] = __expf(pv[c][reg] - mnew);
              rs += pv[c][reg];
            }
          rs += __shfl_xor(rs, 16);
          rs += __shfl_xor(rs, 32);
          ll[qr] = ll[qr] * scl + rs;
          float sr[4];
#pragma unroll
          for (int reg = 0; reg < 4; ++reg) sr[reg] = __shfl(scl, lkg*4 + reg);
#pragma unroll
          for (int db = 0; db < 8; ++db) {
            oacc[qr][db][0] *= sr[0]; oacc[qr][db][1] *= sr[1];
            oacc[qr][db][2] *= sr[2]; oacc[qr][db][3] *= sr[3];
          }
        }
#pragma unroll
        for (int c = 0; c < 4; ++c) {
          unsigned lo = bfu(pv[c][0]) | (bfu(pv[c][1]) << 16);
          unsigned hi = bfu(pv[c][2]) | (bfu(pv[c][3]) << 16);
          *(uint2*)&PsB[(wid*32 + qr*16 + lr) * 72 + c*16 + lkg*4] = make_uint2(lo, hi);
        }
      }
      asm volatile("s_waitcnt lgkmcnt(0)" ::: "memory");
      __builtin_amdgcn_sched_barrier(0);
      bf16x8 pf[2][2];
#pragma unroll
      for (int qr = 0; qr < 2; ++qr)
#pragma unroll
        for (int k2 = 0; k2 < 2; ++k2)
          pf[qr][k2] = *(const bf16x8*)&PsB[(wid*32 + qr*16 + lr) * 72 + k2*32 + lkg*8];
#pragma unroll
      for (int db = 0; db < 8; ++db) {
        bf16x8 vf0 = *(const bf16x8*)&VsB[(db*16 + lr) * 72 + lkg*8];
        bf16x8 vf1 = *(const bf16x8*)&VsB[(db*16 + lr) * 72 + 32 + lkg*8];
#pragma unroll
        for (int qr = 0; qr < 2; ++qr) {
          oacc[qr][db] = mfma16(pf[qr][0], vf0, oacc[qr][db]);
          oacc[qr][db] = mfma16(pf[qr][1], vf1, oacc[qr][db]);
        }
      }
    }
  }

#pragma unroll
  for (int qr = 0; qr < 2; ++qr) {
    const float myinv = 1.0f / ll[qr];
    float li[4];
#pragma unroll
    for (int reg = 0; reg < 4; ++reg) li[reg] = __shfl(myinv, lkg*4 + reg);
#pragma unroll
    for (int reg = 0; reg < 4; ++reg) {
      const int row = q0w + qr*16 + lkg*4 + reg;
      bf16* dst = attnA + ((size_t)(b*LL + row)) * MODEL + h * HDIM;
#pragma unroll
      for (int db = 0; db < 8; ++db)
        dst[db*16 + lr] = __float2bfloat16(oacc[qr][db][reg] * li[reg]);
    }
  }
}

// ---------------- launch ----------------
extern "C" void kernel_launch(void* const* d_in, const int* in_sizes, int n_in,
                              void* d_out, int out_size, void* d_ws, size_t ws_size,
                              hipStream_t stream)
{
  const float* x    = (const float*)d_in[0];
  const float* cosT = (const float*)d_in[1];
  const float* sinT = (const float*)d_in[2];
  const float* Wqkv = (const float*)d_in[3];
  const float* Wc   = (const float*)d_in[4];
  const float* bc   = (const float*)d_in[5];
  float* out = (float*)d_out;

  // workspace layout (bytes):
  //   x16    @ 0         : 16,777,216   (reused as attnA later)
  //   WqkvT  @ 16777216  : 25,165,824
  //   WcT    @ 41943040  :  8,388,608
  //   Qb     @ 50331648  : 16,777,216
  //   Kb     @ 67108864  : 16,777,216
  //   VTb    @ 83886080  : 16,777,216   -> total 100,663,296 B
  if (ws_size < 100663296u) return;
  char* w = (char*)d_ws;
  bf16* x16   = (bf16*)(w);
  bf16* WqkvT = (bf16*)(w + (size_t)16777216);
  bf16* WcT   = (bf16*)(w + (size_t)41943040);
  bf16* Qb    = (bf16*)(w + (size_t)50331648);
  bf16* Kb    = (bf16*)(w + (size_t)67108864);
  bf16* VTb   = (bf16*)(w + (size_t)83886080);
  bf16* attnA = x16;   // overlay: x16 dead after GEMM1

  // allow dynamic LDS (idempotent; not a stream op -> capture-safe)
  hipFuncSetAttribute(reinterpret_cast<const void*>(&k_gemmP<1>),
                      hipFuncAttributeMaxDynamicSharedMemorySize, 65536);
  hipFuncSetAttribute(reinterpret_cast<const void*>(&k_gemmP<2>),
                      hipFuncAttributeMaxDynamicSharedMemorySize, 49152);
  hipFuncSetAttribute(reinterpret_cast<const void*>(&k_attn),
                      hipFuncAttributeMaxDynamicSharedMemorySize, 108544);

  // single fused prep dispatch: cvt (8192) + WqkvT (12288) + WcT (4096)
  k_prep<<<24576, 256, 0, stream>>>(x, x16, Wqkv, WqkvT, Wc, WcT);

  // grid 1536 blocks; 64KB LDS request (48KB used) -> 2 blocks/CU (r24
  // scored-best); r25: m-octant XCD chunking (A chunk 2MB, L2-resident)
  k_gemmP<1><<<(N1/128)*(MTOT/128), 512, 65536, stream>>>(
      x16, WqkvT, MTOT, N1, MODEL,
      nullptr, nullptr, Qb, Kb, VTb, cosT, sinT);

  // grid 8*32 = 256 blocks, 8 waves each, paired q-tiles share staged KV
  k_attn<<<dim3(8, BB*NHEAD), 512, 108544, stream>>>(Qb, Kb, VTb, attnA);

  // grid 16*32 = 512 blocks (2/CU natural, r16-exact map)
  k_gemmP<2><<<(MODEL/128)*(MTOT/128), 512, 49152, stream>>>(
      attnA, WcT, MTOT, MODEL, MODEL,
      out, bc, nullptr, nullptr, nullptr, nullptr, nullptr);
}